// Round 1
// baseline (2643.583 us; speedup 1.0000x reference)
//
#include <hip/hip_runtime.h>

// StyleLossW2: cov/sqrtm(NS,12 iters)/W2-trace loss on MI355X.
// B=8, C=512, HW=16384. Output: 1 fp32 scalar.
//
// Numerics: SYRK in plain bf16 (cov-entry err ~3e-5, loss gradient wrt cov ~0
// by Bures cancellation). Newton-Schulz matmuls in hi/lo bf16 split
// (C = Ah*Bh + Ah*Bl + Al*Bh as a K=3*512 GEMM) ~ fp32 accuracy.
// All NS iterates are symmetric => B^T layout == the matrix itself.

typedef unsigned short u16;
typedef __bf16 bf16_t;
typedef bf16_t bf16x8 __attribute__((ext_vector_type(8)));
typedef float f32x4 __attribute__((ext_vector_type(4)));

#define EPSV 1e-4f

__device__ inline u16 f2b(float f) {
  bf16_t b = (bf16_t)f;
  return __builtin_bit_cast(u16, b);
}
__device__ inline float b2f(u16 u) {
  unsigned v = ((unsigned)u) << 16;
  return __builtin_bit_cast(float, v);
}

// ---------------- convert fp32 -> bf16, compute per-row means ---------------
// grid 8192 (= 2 tensors * 8 b * 512 c), block 256. Row = 16384 elements.
__global__ __launch_bounds__(256) void k_convert(const float* __restrict__ X0,
                                                 const float* __restrict__ X1,
                                                 u16* __restrict__ Xh,
                                                 float* __restrict__ means) {
  int r = blockIdx.x;
  int tid = threadIdx.x;
  const float* src = (r < 4096) ? X0 : X1;
  size_t off = (size_t)(r & 4095) * 16384;
  const float4* s4 = (const float4*)(src + off);
  u16* dst = Xh + (size_t)r * 16384;
  float sum = 0.0f;
#pragma unroll
  for (int i = 0; i < 16; ++i) {
    float4 v = s4[i * 256 + tid];
    sum += v.x + v.y + v.z + v.w;
    ushort4 u;
    u.x = f2b(v.x); u.y = f2b(v.y); u.z = f2b(v.z); u.w = f2b(v.w);
    ((ushort4*)dst)[i * 256 + tid] = u;
  }
  for (int o = 32; o; o >>= 1) sum += __shfl_down(sum, o);
  __shared__ float red[4];
  if ((tid & 63) == 0) red[tid >> 6] = sum;
  __syncthreads();
  if (tid == 0) means[r] = (red[0] + red[1] + red[2] + red[3]) * (1.0f / 16384.0f);
}

// ---------------- generic bf16 MFMA GEMM (B^T layout), 128x128 tile ---------
#define M_COV 0  // out = acc/HW - m_i*m_j + eps*I   (fp32 out)
#define M_AFF 1  // out = c0*acc + c1*I, hi/lo bf16 split store
#define M_SCL 2  // out = acc * aux[mat]             (fp32 out)

struct GP {
  const u16* A0; const u16* A1; const u16* A2;
  const u16* B0; const u16* B1; const u16* B2;
  long sA, sB;            // per-matrix element strides
  int lda, ldb;           // row strides (K dim)
  int nseg, Kseg, mode;
  float* outF; u16* outH; u16* outL;
  const float* aux;       // means[nmat][512] (COV) or per-mat scale (SCL)
  float c0, c1;
};

__global__ __launch_bounds__(256) void k_gemm(GP p, GP q, int split) {
  const GP& j = (blockIdx.x < split) ? p : q;
  int blk = (blockIdx.x < split) ? blockIdx.x : (blockIdx.x - split);
  int mat = blk >> 4;
  int tile = blk & 15;
  int ti = tile >> 2, tj = tile & 3;
  int tid = threadIdx.x, wave = tid >> 6, lane = tid & 63;
  int wm = wave >> 1, wn = wave & 1;

  __shared__ u16 lA[128 * 64];
  __shared__ u16 lB[128 * 64];

  f32x4 acc[4][4] = {};

  const u16* As[3] = { j.A0 + (size_t)mat * j.sA, j.A1 + (size_t)mat * j.sA,
                       j.A2 + (size_t)mat * j.sA };
  const u16* Bs[3] = { j.B0 + (size_t)mat * j.sB, j.B1 + (size_t)mat * j.sB,
                       j.B2 + (size_t)mat * j.sB };

  int srow = lane >> 3;            // 0..7 within 8-row chunk
  int scol = (lane & 7) * 8;       // 8 bf16 = 16B per lane
  int rr = lane & 15, g4 = lane >> 4;

  for (int s = 0; s < j.nseg; ++s) {
    const u16* Ab = As[s] + (size_t)(ti * 128 + srow) * j.lda + scol;
    const u16* Bb = Bs[s] + (size_t)(tj * 128 + srow) * j.ldb + scol;
    for (int k0 = 0; k0 < j.Kseg; k0 += 64) {
#pragma unroll
      for (int it = 0; it < 4; ++it) {
        int chunk = it * 4 + wave;  // wave-uniform
        const u16* ga = Ab + (size_t)(chunk * 8) * j.lda + k0;
        const u16* gb = Bb + (size_t)(chunk * 8) * j.ldb + k0;
        __builtin_amdgcn_global_load_lds(
            (const __attribute__((address_space(1))) unsigned int*)ga,
            (__attribute__((address_space(3))) unsigned int*)&lA[chunk * 512],
            16, 0, 0);
        __builtin_amdgcn_global_load_lds(
            (const __attribute__((address_space(1))) unsigned int*)gb,
            (__attribute__((address_space(3))) unsigned int*)&lB[chunk * 512],
            16, 0, 0);
      }
      __syncthreads();
#pragma unroll
      for (int kk = 0; kk < 2; ++kk) {
        int ko = kk * 32 + g4 * 8;
        bf16x8 af[4], bv[4];
#pragma unroll
        for (int m = 0; m < 4; ++m)
          af[m] = *(const bf16x8*)&lA[(wm * 64 + m * 16 + rr) * 64 + ko];
#pragma unroll
        for (int n = 0; n < 4; ++n)
          bv[n] = *(const bf16x8*)&lB[(wn * 64 + n * 16 + rr) * 64 + ko];
#pragma unroll
        for (int m = 0; m < 4; ++m)
#pragma unroll
          for (int n = 0; n < 4; ++n)
            acc[m][n] = __builtin_amdgcn_mfma_f32_16x16x32_bf16(af[m], bv[n],
                                                                acc[m][n], 0, 0, 0);
      }
      __syncthreads();
    }
  }

  // Epilogue. C/D map (verified m89): col = lane&15, row = (lane>>4)*4 + reg.
  size_t ob = (size_t)mat * 262144;
#pragma unroll
  for (int m = 0; m < 4; ++m)
#pragma unroll
    for (int n = 0; n < 4; ++n)
#pragma unroll
      for (int v4 = 0; v4 < 4; ++v4) {
        int row = ti * 128 + wm * 64 + m * 16 + g4 * 4 + v4;
        int col = tj * 128 + wn * 64 + n * 16 + rr;
        float v = acc[m][n][v4];
        size_t oidx = ob + (size_t)row * 512 + col;
        if (j.mode == M_COV) {
          v = v * (1.0f / 16384.0f) - j.aux[mat * 512 + row] * j.aux[mat * 512 + col]
              + (row == col ? EPSV : 0.0f);
          j.outF[oidx] = v;
        } else if (j.mode == M_AFF) {
          v = j.c0 * v + (row == col ? j.c1 : 0.0f);
          u16 h = f2b(v);
          j.outH[oidx] = h;
          j.outL[oidx] = f2b(v - b2f(h));
        } else {
          j.outF[oidx] = v * j.aux[mat];
        }
      }
}

// ---------------- Frobenius norms: one block per matrix (512x512 fp32) ------
__global__ __launch_bounds__(256) void k_frob(const float* __restrict__ in,
                                              float* __restrict__ norms) {
  int mat = blockIdx.x;
  const float4* p = (const float4*)(in + (size_t)mat * 262144);
  float s = 0.0f;
  for (int i = threadIdx.x; i < 65536; i += 256) {
    float4 v = p[i];
    s += v.x * v.x + v.y * v.y + v.z * v.z + v.w * v.w;
  }
  for (int o = 32; o; o >>= 1) s += __shfl_down(s, o);
  __shared__ float red[4];
  if ((threadIdx.x & 63) == 0) red[threadIdx.x >> 6] = s;
  __syncthreads();
  if (threadIdx.x == 0) norms[mat] = sqrtf(red[0] + red[1] + red[2] + red[3]);
}

// ---------------- scale + hi/lo split (+ optional Z = I init) ---------------
__global__ __launch_bounds__(256) void k_split(const float* __restrict__ in,
                                               const float* __restrict__ norms,
                                               u16* __restrict__ oh, u16* __restrict__ ol,
                                               u16* __restrict__ zh, u16* __restrict__ zl,
                                               int initZ) {
  const size_t n = 8ull * 262144;
  for (size_t idx = (size_t)blockIdx.x * blockDim.x + threadIdx.x; idx < n;
       idx += (size_t)gridDim.x * blockDim.x) {
    int mat = (int)(idx >> 18);
    float sc = norms ? (1.0f / norms[mat]) : 1.0f;
    float v = in[idx] * sc;
    u16 h = f2b(v);
    oh[idx] = h;
    ol[idx] = f2b(v - b2f(h));
    if (initZ) {
      unsigned rc = (unsigned)(idx & 262143u);
      zh[idx] = ((rc >> 9) == (rc & 511u)) ? (u16)0x3F80 : (u16)0;
      zl[idx] = 0;
    }
  }
}

// ---------------- diag(y11 @ t12)*sqrt(norm2) + cov diags -------------------
// grid 1024, block 256 (4 waves -> 4 rows/block). Uses T symmetric (reads row).
__global__ __launch_bounds__(256) void k_diag(const u16* __restrict__ Yh,
                                              const u16* __restrict__ Yl,
                                              const u16* __restrict__ Th,
                                              const u16* __restrict__ Tl,
                                              const float* __restrict__ cov,
                                              const float* __restrict__ norm2,
                                              float* __restrict__ partial) {
  int wave = threadIdx.x >> 6, lane = threadIdx.x & 63;
  int row = blockIdx.x * 4 + wave;      // [0,4096) = b*512 + i
  int mat = row >> 9;
  size_t base = (size_t)row * 512;
  float d = 0.0f;
#pragma unroll
  for (int k = lane; k < 512; k += 64) {
    float y = b2f(Yh[base + k]) + b2f(Yl[base + k]);
    float t = b2f(Th[base + k]) + b2f(Tl[base + k]);
    d += y * t;
  }
  for (int o = 32; o; o >>= 1) d += __shfl_down(d, o);
  if (lane == 0) {
    int i = row & 511;
    size_t dpos = base + i;                        // diag element offset
    float ct = cov[8ull * 262144 + dpos];          // target_cov diag
    float ci = cov[dpos];                          // input cov diag
    partial[row] = ct + ci - 2.0f * d * sqrtf(norm2[mat]);
  }
}

// ---------------- final scalar reduce ---------------------------------------
__global__ __launch_bounds__(256) void k_final(const float* __restrict__ partial,
                                               const float* __restrict__ means,
                                               float* __restrict__ out) {
  float s = 0.0f;
  for (int i = threadIdx.x; i < 4096; i += 256) s += partial[i];
  for (int i = threadIdx.x; i < 4096; i += 256) {
    float dm = means[i] - means[4096 + i];
    s += dm * dm;
  }
  for (int o = 32; o; o >>= 1) s += __shfl_down(s, o);
  __shared__ float red[4];
  if ((threadIdx.x & 63) == 0) red[threadIdx.x >> 6] = s;
  __syncthreads();
  if (threadIdx.x == 0)
    out[0] = (red[0] + red[1] + red[2] + red[3]) * (1.0f / 4096.0f);
}

// ---------------- host ------------------------------------------------------
static GP mkgp(const u16* a0, const u16* a1, const u16* a2,
               const u16* b0, const u16* b1, const u16* b2,
               long sA, long sB, int lda, int ldb, int nseg, int Kseg, int mode,
               float* oF, u16* oH, u16* oL, const float* aux, float c0, float c1) {
  GP g;
  g.A0 = a0; g.A1 = a1; g.A2 = a2;
  g.B0 = b0; g.B1 = b1; g.B2 = b2;
  g.sA = sA; g.sB = sB; g.lda = lda; g.ldb = ldb;
  g.nseg = nseg; g.Kseg = Kseg; g.mode = mode;
  g.outF = oF; g.outH = oH; g.outL = oL; g.aux = aux;
  g.c0 = c0; g.c1 = c1;
  return g;
}

extern "C" void kernel_launch(void* const* d_in, const int* in_sizes, int n_in,
                              void* d_out, int out_size, void* d_ws, size_t ws_size,
                              hipStream_t stream) {
  (void)in_sizes; (void)n_in; (void)out_size; (void)ws_size;
  const float* X0 = (const float*)d_in[0];   // input
  const float* X1 = (const float*)d_in[1];   // target
  float* out = (float*)d_out;

  char* w = (char*)d_ws;
  auto carve = [&](size_t bytes) -> void* {
    void* r = (void*)w;
    w += (bytes + 255) & ~(size_t)255;
    return r;
  };
  const size_t MS = 262144;  // 512*512
  u16*   Xh    = (u16*)carve(2ull * 8 * 512 * 16384 * 2);  // 256 MB
  float* cov   = (float*)carve(16ull * MS * 4);            // [2][8][512][512]
  float* means = (float*)carve(8192 * 4);
  float* norm1 = (float*)carve(256);
  float* norm2 = (float*)carve(256);
  u16* YH[2], *YL[2], *ZH[2], *ZL[2];
  for (int i = 0; i < 2; ++i) {
    YH[i] = (u16*)carve(8 * MS * 2); YL[i] = (u16*)carve(8 * MS * 2);
    ZH[i] = (u16*)carve(8 * MS * 2); ZL[i] = (u16*)carve(8 * MS * 2);
  }
  u16* Th = (u16*)carve(8 * MS * 2); u16* Tl = (u16*)carve(8 * MS * 2);
  u16* Ch = (u16*)carve(8 * MS * 2); u16* Cl = (u16*)carve(8 * MS * 2);
  u16* Ph = (u16*)carve(8 * MS * 2); u16* Pl = (u16*)carve(8 * MS * 2);
  float* Mb = (float*)carve(8 * MS * 4);
  float* partial = (float*)carve(4096 * 4);

  // 1) fp32 -> bf16 + means
  k_convert<<<8192, 256, 0, stream>>>(X0, X1, Xh, means);

  // 2) SYRK -> cov (both tensors, 16 matrices, K=16384)
  {
    GP g = mkgp(Xh, Xh, Xh, Xh, Xh, Xh, (long)(512ll * 16384), (long)(512ll * 16384),
                16384, 16384, 1, 16384, M_COV, cov, nullptr, nullptr, means, 0.f, 0.f);
    k_gemm<<<256, 256, 0, stream>>>(g, g, 256);
  }

  // 3) NS #1 on target_cov
  k_frob<<<8, 256, 0, stream>>>(cov + 8 * MS, norm1);
  k_split<<<2048, 256, 0, stream>>>(cov + 8 * MS, norm1, YH[0], YL[0], ZH[0], ZL[0], 1);
  k_split<<<2048, 256, 0, stream>>>(cov, nullptr, Ch, Cl, nullptr, nullptr, 0);

  int cur = 0;
  for (int it = 1; it <= 12; ++it) {
    GP a = mkgp(ZH[cur], ZH[cur], ZL[cur], YH[cur], YL[cur], YH[cur],
                (long)MS, (long)MS, 512, 512, 3, 512, M_AFF,
                nullptr, Th, Tl, nullptr, -0.5f, 1.5f);
    k_gemm<<<128, 256, 0, stream>>>(a, a, 128);
    GP by = mkgp(YH[cur], YH[cur], YL[cur], Th, Tl, Th,
                 (long)MS, (long)MS, 512, 512, 3, 512, M_AFF,
                 nullptr, YH[1 - cur], YL[1 - cur], nullptr, 1.f, 0.f);
    if (it < 12) {
      GP bz = mkgp(Th, Th, Tl, ZH[cur], ZL[cur], ZH[cur],
                   (long)MS, (long)MS, 512, 512, 3, 512, M_AFF,
                   nullptr, ZH[1 - cur], ZL[1 - cur], nullptr, 1.f, 0.f);
      k_gemm<<<256, 256, 0, stream>>>(by, bz, 128);
    } else {
      k_gemm<<<128, 256, 0, stream>>>(by, by, 128);  // last iter: Y only
    }
    cur ^= 1;
  }
  // Y12 (unit scale sqrt) in YH[cur]/YL[cur]

  // 4) M = norm1 * (Y12 @ C @ Y12)
  {
    GP pp = mkgp(YH[cur], YH[cur], YL[cur], Ch, Cl, Ch,
                 (long)MS, (long)MS, 512, 512, 3, 512, M_AFF,
                 nullptr, Ph, Pl, nullptr, 1.f, 0.f);
    k_gemm<<<128, 256, 0, stream>>>(pp, pp, 128);
    GP mm = mkgp(Ph, Ph, Pl, YH[cur], YL[cur], YH[cur],
                 (long)MS, (long)MS, 512, 512, 3, 512, M_SCL,
                 Mb, nullptr, nullptr, norm1, 0.f, 0.f);
    k_gemm<<<128, 256, 0, stream>>>(mm, mm, 128);
  }

  // 5) NS #2 on M (need diag only at the end)
  k_frob<<<8, 256, 0, stream>>>(Mb, norm2);
  k_split<<<2048, 256, 0, stream>>>(Mb, norm2, YH[0], YL[0], ZH[0], ZL[0], 1);
  cur = 0;
  for (int it = 1; it <= 11; ++it) {
    GP a = mkgp(ZH[cur], ZH[cur], ZL[cur], YH[cur], YL[cur], YH[cur],
                (long)MS, (long)MS, 512, 512, 3, 512, M_AFF,
                nullptr, Th, Tl, nullptr, -0.5f, 1.5f);
    k_gemm<<<128, 256, 0, stream>>>(a, a, 128);
    GP by = mkgp(YH[cur], YH[cur], YL[cur], Th, Tl, Th,
                 (long)MS, (long)MS, 512, 512, 3, 512, M_AFF,
                 nullptr, YH[1 - cur], YL[1 - cur], nullptr, 1.f, 0.f);
    GP bz = mkgp(Th, Th, Tl, ZH[cur], ZL[cur], ZH[cur],
                 (long)MS, (long)MS, 512, 512, 3, 512, M_AFF,
                 nullptr, ZH[1 - cur], ZL[1 - cur], nullptr, 1.f, 0.f);
    k_gemm<<<256, 256, 0, stream>>>(by, bz, 128);
    cur ^= 1;
  }
  {
    GP a12 = mkgp(ZH[cur], ZH[cur], ZL[cur], YH[cur], YL[cur], YH[cur],
                  (long)MS, (long)MS, 512, 512, 3, 512, M_AFF,
                  nullptr, Th, Tl, nullptr, -0.5f, 1.5f);
    k_gemm<<<128, 256, 0, stream>>>(a12, a12, 128);
  }

  // 6) loss
  k_diag<<<1024, 256, 0, stream>>>(YH[cur], YL[cur], Th, Tl, cov, norm2, partial);
  k_final<<<1, 256, 0, stream>>>(partial, means, out);
}

// Round 2
// 1676.084 us; speedup vs baseline: 1.5772x; 1.5772x over previous
//
#include <hip/hip_runtime.h>

// StyleLossW2 on MI355X. B=8, C=512, HW=16384. Output: 1 fp32 scalar.
// Round 2: seg-K-split NS GEMMs (3x blocks, 1/3 serial depth) + combine
// kernels; SYRK K-split=4 + XCD swizzle; LDS XOR-swizzle via pre-swizzled
// global source; NS iterations 12->10 (converged to <1e-7 by MP analysis).

typedef unsigned short u16;
typedef __bf16 bf16_t;
typedef bf16_t bf16x8 __attribute__((ext_vector_type(8)));
typedef float f32x4 __attribute__((ext_vector_type(4)));

#define EPSV 1e-4f
#define MS 262144   // 512*512
#define NITER 10

__device__ inline u16 f2b(float f) {
  bf16_t b = (bf16_t)f;
  return __builtin_bit_cast(u16, b);
}
__device__ inline float b2f(u16 u) {
  unsigned v = ((unsigned)u) << 16;
  return __builtin_bit_cast(float, v);
}

// ---------------- shared 128x128-tile MFMA core -----------------------------
// LDS layout linear for global_load_lds; bank-conflict fix via pre-swizzled
// GLOBAL source column offset (scol ^ (srow<<3)) + matching XOR on ds_read.
template <int LDA, int LDB>
__device__ __forceinline__ void tile_core(const u16* __restrict__ Ab,
                                          const u16* __restrict__ Bb, int ksteps,
                                          u16* lA, u16* lB, f32x4 (&acc)[4][4],
                                          int wave, int lane) {
  int rr = lane & 15, g4 = lane >> 4, wm = wave >> 1, wn = wave & 1;
  int swz = (rr & 7) << 3;
  for (int ks = 0; ks < ksteps; ++ks) {
    int k0 = ks * 64;
#pragma unroll
    for (int it = 0; it < 4; ++it) {
      int chunk = it * 4 + wave;  // wave-uniform
      const u16* ga = Ab + (size_t)(chunk * 8) * LDA + k0;
      const u16* gb = Bb + (size_t)(chunk * 8) * LDB + k0;
      __builtin_amdgcn_global_load_lds(
          (const __attribute__((address_space(1))) unsigned int*)ga,
          (__attribute__((address_space(3))) unsigned int*)&lA[chunk * 512],
          16, 0, 0);
      __builtin_amdgcn_global_load_lds(
          (const __attribute__((address_space(1))) unsigned int*)gb,
          (__attribute__((address_space(3))) unsigned int*)&lB[chunk * 512],
          16, 0, 0);
    }
    __syncthreads();
#pragma unroll
    for (int kk = 0; kk < 2; ++kk) {
      int ko = (kk * 32 + g4 * 8) ^ swz;
      bf16x8 af[4], bv[4];
#pragma unroll
      for (int m = 0; m < 4; ++m)
        af[m] = *(const bf16x8*)&lA[(wm * 64 + m * 16 + rr) * 64 + ko];
#pragma unroll
      for (int n = 0; n < 4; ++n)
        bv[n] = *(const bf16x8*)&lB[(wn * 64 + n * 16 + rr) * 64 + ko];
#pragma unroll
      for (int m = 0; m < 4; ++m)
#pragma unroll
        for (int n = 0; n < 4; ++n)
          acc[m][n] = __builtin_amdgcn_mfma_f32_16x16x32_bf16(af[m], bv[n],
                                                              acc[m][n], 0, 0, 0);
    }
    __syncthreads();
  }
}

// ---------------- convert fp32 -> bf16, per-row means -----------------------
__global__ __launch_bounds__(256) void k_convert(const float* __restrict__ X0,
                                                 const float* __restrict__ X1,
                                                 u16* __restrict__ Xh,
                                                 float* __restrict__ means) {
  int r = blockIdx.x;
  int tid = threadIdx.x;
  const float* src = (r < 4096) ? X0 : X1;
  size_t off = (size_t)(r & 4095) * 16384;
  const float4* s4 = (const float4*)(src + off);
  u16* dst = Xh + (size_t)r * 16384;
  float sum = 0.0f;
#pragma unroll
  for (int i = 0; i < 16; ++i) {
    float4 v = s4[i * 256 + tid];
    sum += v.x + v.y + v.z + v.w;
    ushort4 u;
    u.x = f2b(v.x); u.y = f2b(v.y); u.z = f2b(v.z); u.w = f2b(v.w);
    ((ushort4*)dst)[i * 256 + tid] = u;
  }
  for (int o = 32; o; o >>= 1) sum += __shfl_down(sum, o);
  __shared__ float red[4];
  if ((tid & 63) == 0) red[tid >> 6] = sum;
  __syncthreads();
  if (tid == 0) means[r] = (red[0] + red[1] + red[2] + red[3]) * (1.0f / 16384.0f);
}

// ---------------- SYRK: 1024 jobs = 16 mats x 16 tiles x 4 K-quarters -------
// XCD-bijective swizzle: job = (b&7)*128 + (b>>3) -> each XCD owns 2 matrices.
__global__ __launch_bounds__(256) void k_syrk(const u16* __restrict__ Xh,
                                              float* __restrict__ covP) {
  int b = blockIdx.x;
  int j = ((b & 7) << 7) + (b >> 3);
  int mat = j >> 6, rem = j & 63;
  int ti = rem >> 4, tj = (rem >> 2) & 3, q = rem & 3;
  int tid = threadIdx.x, wave = tid >> 6, lane = tid & 63;
  __shared__ u16 lA[8192], lB[8192];
  f32x4 acc[4][4] = {};
  int srow = lane >> 3;
  int scol = ((lane & 7) * 8) ^ (srow << 3);
  const u16* base = Xh + (size_t)mat * 512 * 16384 + (size_t)q * 4096;
  const u16* Ab = base + (size_t)(ti * 128 + srow) * 16384 + scol;
  const u16* Bb = base + (size_t)(tj * 128 + srow) * 16384 + scol;
  tile_core<16384, 16384>(Ab, Bb, 64, lA, lB, acc, wave, lane);
  int wm = wave >> 1, wn = wave & 1, rr = lane & 15, g4 = lane >> 4;
  float* out = covP + ((size_t)q * 16 + mat) * MS;
#pragma unroll
  for (int m = 0; m < 4; ++m)
#pragma unroll
    for (int n = 0; n < 4; ++n)
#pragma unroll
      for (int v4 = 0; v4 < 4; ++v4) {
        int row = ti * 128 + wm * 64 + m * 16 + g4 * 4 + v4;
        int col = tj * 128 + wn * 64 + n * 16 + rr;
        out[(size_t)row * 512 + col] = acc[m][n][v4];
      }
}

// ---------------- NS seg-split GEMM: jobs = 8 mats x 3 segs x 16 tiles ------
struct NJ {
  const u16 *Ah, *Al, *Bh, *Bl;
  float *P0, *P1, *P2;
};

__global__ __launch_bounds__(256) void k_nsgemm(NJ p, NJ q, int split) {
  int b = blockIdx.x;
  const NJ j = (b < split) ? p : q;
  int blk = (b < split) ? b : b - split;
  int mat = blk / 48, rem = blk % 48;
  int seg = rem >> 4, tile = rem & 15;
  int ti = tile >> 2, tj = tile & 3;
  const u16* A = (seg == 2) ? j.Al : j.Ah;
  const u16* B = (seg == 1) ? j.Bl : j.Bh;
  float* P = (seg == 0) ? j.P0 : (seg == 1) ? j.P1 : j.P2;
  int tid = threadIdx.x, wave = tid >> 6, lane = tid & 63;
  __shared__ u16 lA[8192], lB[8192];
  f32x4 acc[4][4] = {};
  int srow = lane >> 3;
  int scol = ((lane & 7) * 8) ^ (srow << 3);
  const u16* Ab = A + (size_t)mat * MS + (size_t)(ti * 128 + srow) * 512 + scol;
  const u16* Bb = B + (size_t)mat * MS + (size_t)(tj * 128 + srow) * 512 + scol;
  tile_core<512, 512>(Ab, Bb, 8, lA, lB, acc, wave, lane);
  int wm = wave >> 1, wn = wave & 1, rr = lane & 15, g4 = lane >> 4;
  float* out = P + (size_t)mat * MS;
#pragma unroll
  for (int m = 0; m < 4; ++m)
#pragma unroll
    for (int n = 0; n < 4; ++n)
#pragma unroll
      for (int v4 = 0; v4 < 4; ++v4) {
        int row = ti * 128 + wm * 64 + m * 16 + g4 * 4 + v4;
        int col = tj * 128 + wn * 64 + n * 16 + rr;
        out[(size_t)row * 512 + col] = acc[m][n][v4];
      }
}

// ---------------- cov finish: sum 4 K-quarters, /HW - mean outer + eps I ----
__global__ __launch_bounds__(256) void k_covfin(const float* __restrict__ covP,
                                                const float* __restrict__ means,
                                                float* __restrict__ cov) {
  const int NF4 = 16 * MS / 4;  // 1048576
  const float4* P0 = (const float4*)covP;
  const float4* P1 = P0 + NF4;
  const float4* P2 = P1 + NF4;
  const float4* P3 = P2 + NF4;
  for (int i4 = blockIdx.x * 256 + threadIdx.x; i4 < NF4; i4 += gridDim.x * 256) {
    float4 a = P0[i4], b = P1[i4], c = P2[i4], d = P3[i4];
    int mat = i4 >> 16;
    int r = (i4 >> 7) & 511;
    int cb = (i4 & 127) * 4;
    float mr = means[mat * 512 + r];
    float v[4] = {a.x + b.x + c.x + d.x, a.y + b.y + c.y + d.y,
                  a.z + b.z + c.z + d.z, a.w + b.w + c.w + d.w};
    float4 o;
    float* po = &o.x;
#pragma unroll
    for (int t = 0; t < 4; ++t) {
      float vv = v[t] * (1.0f / 16384.0f) - mr * means[mat * 512 + cb + t];
      if (r == cb + t) vv += EPSV;
      po[t] = vv;
    }
    ((float4*)cov)[i4] = o;
  }
}

// ---------------- NS combine: out = c0*(P0+P1+P2) + c1*I ; split or fp32 ----
struct AJ {
  const float *P0, *P1, *P2;
  u16 *oH, *oL;
  float* oF;
  const float* scale;  // per-mat scale for oF path
  float c0, c1;
};

__global__ __launch_bounds__(256) void k_aff3(AJ p, AJ q, int split) {
  bool second = (int)blockIdx.x >= split;
  const AJ j = second ? q : p;
  int nb = second ? (gridDim.x - split) : split;
  int b0 = second ? (blockIdx.x - split) : blockIdx.x;
  const int NF4 = 8 * MS / 4;  // 524288
  const float4* P0 = (const float4*)j.P0;
  const float4* P1 = (const float4*)j.P1;
  const float4* P2 = (const float4*)j.P2;
  for (int i4 = b0 * 256 + threadIdx.x; i4 < NF4; i4 += nb * 256) {
    float4 a = P0[i4], b = P1[i4], c = P2[i4];
    int mat = i4 >> 16;
    int r = (i4 >> 7) & 511;
    int cb = (i4 & 127) * 4;
    float v[4] = {a.x + b.x + c.x, a.y + b.y + c.y, a.z + b.z + c.z,
                  a.w + b.w + c.w};
#pragma unroll
    for (int t = 0; t < 4; ++t) {
      v[t] = j.c0 * v[t] + ((r == cb + t) ? j.c1 : 0.0f);
    }
    if (j.oF) {
      float sc = j.scale ? j.scale[mat] : 1.0f;
      float4 o = {v[0] * sc, v[1] * sc, v[2] * sc, v[3] * sc};
      ((float4*)j.oF)[i4] = o;
    } else {
      ushort4 h, l;
      unsigned short* ph = &h.x;
      unsigned short* pl = &l.x;
#pragma unroll
      for (int t = 0; t < 4; ++t) {
        u16 hh = f2b(v[t]);
        ph[t] = hh;
        pl[t] = f2b(v[t] - b2f(hh));
      }
      ((ushort4*)j.oH)[i4] = h;
      ((ushort4*)j.oL)[i4] = l;
    }
  }
}

// ---------------- Frobenius norms -------------------------------------------
__global__ __launch_bounds__(256) void k_frob(const float* __restrict__ in,
                                              float* __restrict__ norms) {
  int mat = blockIdx.x;
  const float4* p = (const float4*)(in + (size_t)mat * MS);
  float s = 0.0f;
  for (int i = threadIdx.x; i < 65536; i += 256) {
    float4 v = p[i];
    s += v.x * v.x + v.y * v.y + v.z * v.z + v.w * v.w;
  }
  for (int o = 32; o; o >>= 1) s += __shfl_down(s, o);
  __shared__ float red[4];
  if ((threadIdx.x & 63) == 0) red[threadIdx.x >> 6] = s;
  __syncthreads();
  if (threadIdx.x == 0) norms[mat] = sqrtf(red[0] + red[1] + red[2] + red[3]);
}

// ---------------- scale + hi/lo split (+ optional Z = I init) ---------------
__global__ __launch_bounds__(256) void k_split(const float* __restrict__ in,
                                               const float* __restrict__ norms,
                                               u16* __restrict__ oh, u16* __restrict__ ol,
                                               u16* __restrict__ zh, u16* __restrict__ zl,
                                               int initZ) {
  const size_t n = 8ull * MS;
  for (size_t idx = (size_t)blockIdx.x * blockDim.x + threadIdx.x; idx < n;
       idx += (size_t)gridDim.x * blockDim.x) {
    int mat = (int)(idx >> 18);
    float sc = norms ? (1.0f / norms[mat]) : 1.0f;
    float v = in[idx] * sc;
    u16 h = f2b(v);
    oh[idx] = h;
    ol[idx] = f2b(v - b2f(h));
    if (initZ) {
      unsigned rc = (unsigned)(idx & 262143u);
      zh[idx] = ((rc >> 9) == (rc & 511u)) ? (u16)0x3F80 : (u16)0;
      zl[idx] = 0;
    }
  }
}

// ---------------- diag(Y @ T)*sqrt(norm2) + cov diags -----------------------
__global__ __launch_bounds__(256) void k_diag(const u16* __restrict__ Yh,
                                              const u16* __restrict__ Yl,
                                              const u16* __restrict__ Th,
                                              const u16* __restrict__ Tl,
                                              const float* __restrict__ cov,
                                              const float* __restrict__ norm2,
                                              float* __restrict__ partial) {
  int wave = threadIdx.x >> 6, lane = threadIdx.x & 63;
  int row = blockIdx.x * 4 + wave;  // [0,4096) = b*512 + i
  int mat = row >> 9;
  size_t base = (size_t)row * 512;
  float d = 0.0f;
#pragma unroll
  for (int k = lane; k < 512; k += 64) {
    float y = b2f(Yh[base + k]) + b2f(Yl[base + k]);
    float t = b2f(Th[base + k]) + b2f(Tl[base + k]);
    d += y * t;
  }
  for (int o = 32; o; o >>= 1) d += __shfl_down(d, o);
  if (lane == 0) {
    int i = row & 511;
    size_t dpos = base + i;
    float ct = cov[8ull * MS + dpos];
    float ci = cov[dpos];
    partial[row] = ct + ci - 2.0f * d * sqrtf(norm2[mat]);
  }
}

// ---------------- final scalar reduce ---------------------------------------
__global__ __launch_bounds__(256) void k_final(const float* __restrict__ partial,
                                               const float* __restrict__ means,
                                               float* __restrict__ out) {
  float s = 0.0f;
  for (int i = threadIdx.x; i < 4096; i += 256) s += partial[i];
  for (int i = threadIdx.x; i < 4096; i += 256) {
    float dm = means[i] - means[4096 + i];
    s += dm * dm;
  }
  for (int o = 32; o; o >>= 1) s += __shfl_down(s, o);
  __shared__ float red[4];
  if ((threadIdx.x & 63) == 0) red[threadIdx.x >> 6] = s;
  __syncthreads();
  if (threadIdx.x == 0)
    out[0] = (red[0] + red[1] + red[2] + red[3]) * (1.0f / 4096.0f);
}

// ---------------- host ------------------------------------------------------
extern "C" void kernel_launch(void* const* d_in, const int* in_sizes, int n_in,
                              void* d_out, int out_size, void* d_ws, size_t ws_size,
                              hipStream_t stream) {
  (void)in_sizes; (void)n_in; (void)out_size; (void)ws_size;
  const float* X0 = (const float*)d_in[0];
  const float* X1 = (const float*)d_in[1];
  float* out = (float*)d_out;

  char* w = (char*)d_ws;
  auto carve = [&](size_t bytes) -> void* {
    void* r = (void*)w;
    w += (bytes + 255) & ~(size_t)255;
    return r;
  };
  u16*   Xh   = (u16*)carve(2ull * 8 * 512 * 16384 * 2);  // 256 MiB
  float* cov  = (float*)carve(16ull * MS * 4);            // 16 MiB
  float* U    = (float*)carve(4ull * 16 * MS * 4);        // 64 MiB: covP / NS partials
  float* means = (float*)carve(8192 * 4);
  float* norm1 = (float*)carve(256);
  float* norm2 = (float*)carve(256);
  u16 *YH[2], *YL[2], *ZH[2], *ZL[2];
  for (int i = 0; i < 2; ++i) {
    YH[i] = (u16*)carve(8 * MS * 2); YL[i] = (u16*)carve(8 * MS * 2);
    ZH[i] = (u16*)carve(8 * MS * 2); ZL[i] = (u16*)carve(8 * MS * 2);
  }
  u16* Th = (u16*)carve(8 * MS * 2); u16* Tl = (u16*)carve(8 * MS * 2);
  u16* Ch = (u16*)carve(8 * MS * 2); u16* Cl = (u16*)carve(8 * MS * 2);
  u16* Ph = (u16*)carve(8 * MS * 2); u16* Pl = (u16*)carve(8 * MS * 2);
  float* Mb = (float*)carve(8 * MS * 4);
  float* partial = (float*)carve(4096 * 4);

  // NS partial buffers live inside U (covP consumed before NS starts)
  float* PT0 = U;                 // 2M floats each
  float* PT1 = U + 2 * 1048576;
  float* PT2 = U + 4 * 1048576;
  float* PZ0 = U + 6 * 1048576;
  float* PZ1 = U + 8 * 1048576;
  float* PZ2 = U + 10 * 1048576;

  // 1) fp32 -> bf16 + means
  k_convert<<<8192, 256, 0, stream>>>(X0, X1, Xh, means);

  // 2) SYRK (K-split 4) + finish
  k_syrk<<<1024, 256, 0, stream>>>(Xh, U);
  k_covfin<<<2048, 256, 0, stream>>>(U, means, cov);

  // 3) NS #1 on target_cov (mats 8..15)
  k_frob<<<8, 256, 0, stream>>>(cov + 8 * MS, norm1);
  k_split<<<2048, 256, 0, stream>>>(cov + 8 * MS, norm1, YH[0], YL[0], ZH[0], ZL[0], 1);
  k_split<<<2048, 256, 0, stream>>>(cov, nullptr, Ch, Cl, nullptr, nullptr, 0);

  int cur = 0;
  for (int it = 0; it < NITER; ++it) {
    NJ tj = {ZH[cur], ZL[cur], YH[cur], YL[cur], PT0, PT1, PT2};
    k_nsgemm<<<384, 256, 0, stream>>>(tj, tj, 384);
    AJ tc = {PT0, PT1, PT2, Th, Tl, nullptr, nullptr, -0.5f, 1.5f};
    k_aff3<<<1024, 256, 0, stream>>>(tc, tc, 1024);
    if (it < NITER - 1) {
      NJ yj = {YH[cur], YL[cur], Th, Tl, PT0, PT1, PT2};  // PY aliases PT
      NJ zj = {Th, Tl, ZH[cur], ZL[cur], PZ0, PZ1, PZ2};
      k_nsgemm<<<768, 256, 0, stream>>>(yj, zj, 384);
      AJ yc = {PT0, PT1, PT2, YH[1 - cur], YL[1 - cur], nullptr, nullptr, 1.f, 0.f};
      AJ zc = {PZ0, PZ1, PZ2, ZH[1 - cur], ZL[1 - cur], nullptr, nullptr, 1.f, 0.f};
      k_aff3<<<2048, 256, 0, stream>>>(yc, zc, 1024);
    } else {
      NJ yj = {YH[cur], YL[cur], Th, Tl, PT0, PT1, PT2};
      k_nsgemm<<<384, 256, 0, stream>>>(yj, yj, 384);
      AJ yc = {PT0, PT1, PT2, YH[1 - cur], YL[1 - cur], nullptr, nullptr, 1.f, 0.f};
      k_aff3<<<1024, 256, 0, stream>>>(yc, yc, 1024);
    }
    cur ^= 1;
  }
  // Y_final (unit-scale sqrt) in YH[cur]/YL[cur]

  // 4) M = norm1 * (Y @ C @ Y)
  {
    NJ pj = {YH[cur], YL[cur], Ch, Cl, PT0, PT1, PT2};
    k_nsgemm<<<384, 256, 0, stream>>>(pj, pj, 384);
    AJ pc = {PT0, PT1, PT2, Ph, Pl, nullptr, nullptr, 1.f, 0.f};
    k_aff3<<<1024, 256, 0, stream>>>(pc, pc, 1024);
    NJ mj = {Ph, Pl, YH[cur], YL[cur], PT0, PT1, PT2};
    k_nsgemm<<<384, 256, 0, stream>>>(mj, mj, 384);
    AJ mc = {PT0, PT1, PT2, nullptr, nullptr, Mb, norm1, 1.f, 0.f};
    k_aff3<<<1024, 256, 0, stream>>>(mc, mc, 1024);
  }

  // 5) NS #2 on M; need diag(Y_final) only
  k_frob<<<8, 256, 0, stream>>>(Mb, norm2);
  k_split<<<2048, 256, 0, stream>>>(Mb, norm2, YH[0], YL[0], ZH[0], ZL[0], 1);
  cur = 0;
  for (int it = 0; it < NITER - 1; ++it) {  // 9 full iterations
    NJ tj = {ZH[cur], ZL[cur], YH[cur], YL[cur], PT0, PT1, PT2};
    k_nsgemm<<<384, 256, 0, stream>>>(tj, tj, 384);
    AJ tc = {PT0, PT1, PT2, Th, Tl, nullptr, nullptr, -0.5f, 1.5f};
    k_aff3<<<1024, 256, 0, stream>>>(tc, tc, 1024);
    NJ yj = {YH[cur], YL[cur], Th, Tl, PT0, PT1, PT2};
    NJ zj = {Th, Tl, ZH[cur], ZL[cur], PZ0, PZ1, PZ2};
    k_nsgemm<<<768, 256, 0, stream>>>(yj, zj, 384);
    AJ yc = {PT0, PT1, PT2, YH[1 - cur], YL[1 - cur], nullptr, nullptr, 1.f, 0.f};
    AJ zc = {PZ0, PZ1, PZ2, ZH[1 - cur], ZL[1 - cur], nullptr, nullptr, 1.f, 0.f};
    k_aff3<<<2048, 256, 0, stream>>>(yc, zc, 1024);
    cur ^= 1;
  }
  {  // final T, then diag(Y9 @ T9) = diag(Y10)
    NJ tj = {ZH[cur], ZL[cur], YH[cur], YL[cur], PT0, PT1, PT2};
    k_nsgemm<<<384, 256, 0, stream>>>(tj, tj, 384);
    AJ tc = {PT0, PT1, PT2, Th, Tl, nullptr, nullptr, -0.5f, 1.5f};
    k_aff3<<<1024, 256, 0, stream>>>(tc, tc, 1024);
  }

  // 6) loss
  k_diag<<<1024, 256, 0, stream>>>(YH[cur], YL[cur], Th, Tl, cov, norm2, partial);
  k_final<<<1, 256, 0, stream>>>(partial, means, out);
}

// Round 3
// 1318.880 us; speedup vs baseline: 2.0044x; 1.2708x over previous
//
#include <hip/hip_runtime.h>

// StyleLossW2 on MI355X. B=8, C=512, HW=16384. Output: 1 fp32 scalar.
// Round 3: fused NS GEMM (K=1536 hi/lo segs in-block, affine+split epilogue,
// no fp32 partials), 2-phase double-buffered LDS core (T3-minimum),
// 64x64 NS tiles for occupancy, XCD-bijective swizzles everywhere.

typedef unsigned short u16;
typedef __bf16 bf16_t;
typedef bf16_t bf16x8 __attribute__((ext_vector_type(8)));
typedef float f32x4 __attribute__((ext_vector_type(4)));

#define EPSV 1e-4f
#define MS 262144   // 512*512
#define NITER 10

__device__ inline u16 f2b(float f) {
  bf16_t b = (bf16_t)f;
  return __builtin_bit_cast(u16, b);
}
__device__ inline float b2f(u16 u) {
  unsigned v = ((unsigned)u) << 16;
  return __builtin_bit_cast(float, v);
}

// ---------------- 2-phase double-buffered MFMA tile core --------------------
// FR: 16x16 fragments per wave dim (2 -> 64x64 tile, 4 -> 128x128 tile).
// A/B pointers are per-segment, pre-offset to (tile row + srow, swizzled col).
// LDS linear (global_load_lds); bank-conflict-free via pre-swizzled global
// source col (scol ^ (srow<<3)) + matching XOR on ds_read (verified r2: 0).
template <int FR, int LDA, int LDB, int SPS>
__device__ __forceinline__ void core2(const u16* A0, const u16* A1, const u16* A2,
                                      const u16* B0, const u16* B1, const u16* B2,
                                      int nsteps, u16* lds, f32x4 (&acc)[FR][FR],
                                      int wave, int lane) {
  const int TS = FR * 32 * 64;  // elems per tile
  const u16* As[3] = {A0, A1, A2};
  const u16* Bs[3] = {B0, B1, B2};
  int rr = lane & 15, g4 = lane >> 4, wm = wave >> 1, wn = wave & 1;
  int swz = (rr & 7) << 3;
  // prologue: stage ks=0 into buf 0
#pragma unroll
  for (int it = 0; it < FR; ++it) {
    int chunk = it * 4 + wave;
    __builtin_amdgcn_global_load_lds(
        (const __attribute__((address_space(1))) unsigned int*)(A0 + (size_t)(chunk * 8) * LDA),
        (__attribute__((address_space(3))) unsigned int*)&lds[chunk * 512], 16, 0, 0);
    __builtin_amdgcn_global_load_lds(
        (const __attribute__((address_space(1))) unsigned int*)(B0 + (size_t)(chunk * 8) * LDB),
        (__attribute__((address_space(3))) unsigned int*)&lds[TS + chunk * 512], 16, 0, 0);
  }
  __syncthreads();
  int buf = 0;
  for (int ks = 0; ks < nsteps; ++ks) {
    if (ks + 1 < nsteps) {  // prefetch next K-step into the other buffer
      int kn = ks + 1;
      int seg = kn / SPS;
      int k0 = (kn % SPS) * 64;
      const u16* A = As[seg];
      const u16* B = Bs[seg];
      u16* dst = lds + (buf ^ 1) * 2 * TS;
#pragma unroll
      for (int it = 0; it < FR; ++it) {
        int chunk = it * 4 + wave;
        __builtin_amdgcn_global_load_lds(
            (const __attribute__((address_space(1))) unsigned int*)(A + (size_t)(chunk * 8) * LDA + k0),
            (__attribute__((address_space(3))) unsigned int*)&dst[chunk * 512], 16, 0, 0);
        __builtin_amdgcn_global_load_lds(
            (const __attribute__((address_space(1))) unsigned int*)(B + (size_t)(chunk * 8) * LDB + k0),
            (__attribute__((address_space(3))) unsigned int*)&dst[TS + chunk * 512], 16, 0, 0);
      }
    }
    const u16* lb = lds + buf * 2 * TS;
#pragma unroll
    for (int kk = 0; kk < 2; ++kk) {
      int ko = (kk * 32 + g4 * 8) ^ swz;
      bf16x8 af[FR], bv[FR];
#pragma unroll
      for (int m = 0; m < FR; ++m)
        af[m] = *(const bf16x8*)&lb[(wm * FR * 16 + m * 16 + rr) * 64 + ko];
#pragma unroll
      for (int n = 0; n < FR; ++n)
        bv[n] = *(const bf16x8*)&lb[TS + (wn * FR * 16 + n * 16 + rr) * 64 + ko];
#pragma unroll
      for (int m = 0; m < FR; ++m)
#pragma unroll
        for (int n = 0; n < FR; ++n)
          acc[m][n] = __builtin_amdgcn_mfma_f32_16x16x32_bf16(af[m], bv[n],
                                                              acc[m][n], 0, 0, 0);
    }
    __syncthreads();  // drains vmcnt(0): prefetch landed; all reads of buf done
    buf ^= 1;
  }
}

// ---------------- convert fp32 -> bf16, per-row means -----------------------
__global__ __launch_bounds__(256) void k_convert(const float* __restrict__ X0,
                                                 const float* __restrict__ X1,
                                                 u16* __restrict__ Xh,
                                                 float* __restrict__ means) {
  int r = blockIdx.x;
  int tid = threadIdx.x;
  const float* src = (r < 4096) ? X0 : X1;
  size_t off = (size_t)(r & 4095) * 16384;
  const float4* s4 = (const float4*)(src + off);
  u16* dst = Xh + (size_t)r * 16384;
  float sum = 0.0f;
#pragma unroll
  for (int i = 0; i < 16; ++i) {
    float4 v = s4[i * 256 + tid];
    sum += v.x + v.y + v.z + v.w;
    ushort4 u;
    u.x = f2b(v.x); u.y = f2b(v.y); u.z = f2b(v.z); u.w = f2b(v.w);
    ((ushort4*)dst)[i * 256 + tid] = u;
  }
  for (int o = 32; o; o >>= 1) sum += __shfl_down(sum, o);
  __shared__ float red[4];
  if ((tid & 63) == 0) red[tid >> 6] = sum;
  __syncthreads();
  if (tid == 0) means[r] = (red[0] + red[1] + red[2] + red[3]) * (1.0f / 16384.0f);
}

// ---------------- SYRK: 1024 jobs = 16 mats x 16 tiles x 4 K-quarters -------
__global__ __launch_bounds__(256) void k_syrk(const u16* __restrict__ Xh,
                                              float* __restrict__ covP) {
  int b = blockIdx.x;
  int jid = ((b & 7) << 7) + (b >> 3);  // XCD swizzle: 2 mats per XCD
  int mat = jid >> 6, rem = jid & 63;
  int ti = rem >> 4, tj = (rem >> 2) & 3, q = rem & 3;
  int tid = threadIdx.x, wave = tid >> 6, lane = tid & 63;
  __shared__ u16 lds[2 * 2 * 128 * 64];  // 64 KB (double-buffered)
  f32x4 acc[4][4] = {};
  int srow = lane >> 3;
  int scol = ((lane & 7) * 8) ^ (srow << 3);
  const u16* base = Xh + (size_t)mat * 512 * 16384 + (size_t)q * 4096;
  const u16* Ab = base + (size_t)(ti * 128 + srow) * 16384 + scol;
  const u16* Bb = base + (size_t)(tj * 128 + srow) * 16384 + scol;
  core2<4, 16384, 16384, 64>(Ab, Ab, Ab, Bb, Bb, Bb, 64, lds, acc, wave, lane);
  int wm = wave >> 1, wn = wave & 1, rr = lane & 15, g4 = lane >> 4;
  float* out = covP + ((size_t)q * 16 + mat) * MS;
#pragma unroll
  for (int m = 0; m < 4; ++m)
#pragma unroll
    for (int n = 0; n < 4; ++n)
#pragma unroll
      for (int v4 = 0; v4 < 4; ++v4) {
        int row = ti * 128 + wm * 64 + m * 16 + g4 * 4 + v4;
        int col = tj * 128 + wn * 64 + n * 16 + rr;
        out[(size_t)row * 512 + col] = acc[m][n][v4];
      }
}

// ---------------- fused NS GEMM: K=1536 (3 hi/lo segs), 64x64 tiles ---------
// out = c0*(Ah*Bh + Ah*Bl + Al*Bh) + c1*I; store bf16 hi/lo or fp32*scale.
struct FJ {
  const u16 *Ah, *Al, *Bh, *Bl;
  u16 *oH, *oL;
  float* oF;
  const float* scale;
  float c0, c1;
};

__global__ __launch_bounds__(256) void k_nsfused(FJ p, FJ q, int split) {
  int sid = ((blockIdx.x & 7) * (gridDim.x >> 3)) + (blockIdx.x >> 3);  // XCD swz
  const FJ j = (sid < split) ? p : q;
  int blk = (sid < split) ? sid : sid - split;
  int mat = blk >> 6, tile = blk & 63;
  int ti = tile >> 3, tj = tile & 7;
  int tid = threadIdx.x, wave = tid >> 6, lane = tid & 63;
  __shared__ u16 lds[2 * 2 * 64 * 64];  // 32 KB
  f32x4 acc[2][2] = {};
  int srow = lane >> 3;
  int scol = ((lane & 7) * 8) ^ (srow << 3);
  size_t mo = (size_t)mat * MS;
  size_t ao = mo + (size_t)(ti * 64 + srow) * 512 + scol;
  size_t bo = mo + (size_t)(tj * 64 + srow) * 512 + scol;
  const u16* A0 = j.Ah + ao;
  const u16* A2 = j.Al + ao;
  const u16* B0 = j.Bh + bo;
  const u16* B1 = j.Bl + bo;
  // segs: (Ah,Bh), (Ah,Bl), (Al,Bh)
  core2<2, 512, 512, 8>(A0, A0, A2, B0, B1, B0, 24, lds, acc, wave, lane);
  int wm = wave >> 1, wn = wave & 1, rr = lane & 15, g4 = lane >> 4;
#pragma unroll
  for (int m = 0; m < 2; ++m)
#pragma unroll
    for (int n = 0; n < 2; ++n)
#pragma unroll
      for (int v4 = 0; v4 < 4; ++v4) {
        int row = ti * 64 + wm * 32 + m * 16 + g4 * 4 + v4;
        int col = tj * 64 + wn * 32 + n * 16 + rr;
        float v = j.c0 * acc[m][n][v4] + (row == col ? j.c1 : 0.0f);
        size_t idx = mo + (size_t)row * 512 + col;
        if (j.oF) {
          j.oF[idx] = v * (j.scale ? j.scale[mat] : 1.0f);
        } else {
          u16 h = f2b(v);
          j.oH[idx] = h;
          j.oL[idx] = f2b(v - b2f(h));
        }
      }
}

// ---------------- cov finish: sum 4 K-quarters, /HW - mean outer + eps I ----
__global__ __launch_bounds__(256) void k_covfin(const float* __restrict__ covP,
                                                const float* __restrict__ means,
                                                float* __restrict__ cov) {
  const int NF4 = 16 * MS / 4;  // 1048576
  const float4* P0 = (const float4*)covP;
  const float4* P1 = P0 + NF4;
  const float4* P2 = P1 + NF4;
  const float4* P3 = P2 + NF4;
  for (int i4 = blockIdx.x * 256 + threadIdx.x; i4 < NF4; i4 += gridDim.x * 256) {
    float4 a = P0[i4], b = P1[i4], c = P2[i4], d = P3[i4];
    int mat = i4 >> 16;
    int r = (i4 >> 7) & 511;
    int cb = (i4 & 127) * 4;
    float mr = means[mat * 512 + r];
    float v[4] = {a.x + b.x + c.x + d.x, a.y + b.y + c.y + d.y,
                  a.z + b.z + c.z + d.z, a.w + b.w + c.w + d.w};
    float4 o;
    float* po = &o.x;
#pragma unroll
    for (int t = 0; t < 4; ++t) {
      float vv = v[t] * (1.0f / 16384.0f) - mr * means[mat * 512 + cb + t];
      if (r == cb + t) vv += EPSV;
      po[t] = vv;
    }
    ((float4*)cov)[i4] = o;
  }
}

// ---------------- Frobenius norms -------------------------------------------
__global__ __launch_bounds__(256) void k_frob(const float* __restrict__ in,
                                              float* __restrict__ norms) {
  int mat = blockIdx.x;
  const float4* p = (const float4*)(in + (size_t)mat * MS);
  float s = 0.0f;
  for (int i = threadIdx.x; i < 65536; i += 256) {
    float4 v = p[i];
    s += v.x * v.x + v.y * v.y + v.z * v.z + v.w * v.w;
  }
  for (int o = 32; o; o >>= 1) s += __shfl_down(s, o);
  __shared__ float red[4];
  if ((threadIdx.x & 63) == 0) red[threadIdx.x >> 6] = s;
  __syncthreads();
  if (threadIdx.x == 0) norms[mat] = sqrtf(red[0] + red[1] + red[2] + red[3]);
}

// ---------------- scale + hi/lo split (+ optional Z = I init) ---------------
__global__ __launch_bounds__(256) void k_split(const float* __restrict__ in,
                                               const float* __restrict__ norms,
                                               u16* __restrict__ oh, u16* __restrict__ ol,
                                               u16* __restrict__ zh, u16* __restrict__ zl,
                                               int initZ) {
  const size_t n = 8ull * MS;
  for (size_t idx = (size_t)blockIdx.x * blockDim.x + threadIdx.x; idx < n;
       idx += (size_t)gridDim.x * blockDim.x) {
    int mat = (int)(idx >> 18);
    float sc = norms ? (1.0f / norms[mat]) : 1.0f;
    float v = in[idx] * sc;
    u16 h = f2b(v);
    oh[idx] = h;
    ol[idx] = f2b(v - b2f(h));
    if (initZ) {
      unsigned rc = (unsigned)(idx & 262143u);
      zh[idx] = ((rc >> 9) == (rc & 511u)) ? (u16)0x3F80 : (u16)0;
      zl[idx] = 0;
    }
  }
}

// ---------------- diag(Y @ T)*sqrt(norm2) + cov diags -----------------------
__global__ __launch_bounds__(256) void k_diag(const u16* __restrict__ Yh,
                                              const u16* __restrict__ Yl,
                                              const u16* __restrict__ Th,
                                              const u16* __restrict__ Tl,
                                              const float* __restrict__ cov,
                                              const float* __restrict__ norm2,
                                              float* __restrict__ partial) {
  int wave = threadIdx.x >> 6, lane = threadIdx.x & 63;
  int row = blockIdx.x * 4 + wave;  // [0,4096) = b*512 + i
  int mat = row >> 9;
  size_t base = (size_t)row * 512;
  float d = 0.0f;
#pragma unroll
  for (int k = lane; k < 512; k += 64) {
    float y = b2f(Yh[base + k]) + b2f(Yl[base + k]);
    float t = b2f(Th[base + k]) + b2f(Tl[base + k]);
    d += y * t;
  }
  for (int o = 32; o; o >>= 1) d += __shfl_down(d, o);
  if (lane == 0) {
    int i = row & 511;
    size_t dpos = base + i;
    float ct = cov[8ull * MS + dpos];
    float ci = cov[dpos];
    partial[row] = ct + ci - 2.0f * d * sqrtf(norm2[mat]);
  }
}

// ---------------- final scalar reduce ---------------------------------------
__global__ __launch_bounds__(256) void k_final(const float* __restrict__ partial,
                                               const float* __restrict__ means,
                                               float* __restrict__ out) {
  float s = 0.0f;
  for (int i = threadIdx.x; i < 4096; i += 256) s += partial[i];
  for (int i = threadIdx.x; i < 4096; i += 256) {
    float dm = means[i] - means[4096 + i];
    s += dm * dm;
  }
  for (int o = 32; o; o >>= 1) s += __shfl_down(s, o);
  __shared__ float red[4];
  if ((threadIdx.x & 63) == 0) red[threadIdx.x >> 6] = s;
  __syncthreads();
  if (threadIdx.x == 0)
    out[0] = (red[0] + red[1] + red[2] + red[3]) * (1.0f / 4096.0f);
}

// ---------------- host ------------------------------------------------------
extern "C" void kernel_launch(void* const* d_in, const int* in_sizes, int n_in,
                              void* d_out, int out_size, void* d_ws, size_t ws_size,
                              hipStream_t stream) {
  (void)in_sizes; (void)n_in; (void)out_size; (void)ws_size;
  const float* X0 = (const float*)d_in[0];
  const float* X1 = (const float*)d_in[1];
  float* out = (float*)d_out;

  char* w = (char*)d_ws;
  auto carve = [&](size_t bytes) -> void* {
    void* r = (void*)w;
    w += (bytes + 255) & ~(size_t)255;
    return r;
  };
  u16*   Xh   = (u16*)carve(2ull * 8 * 512 * 16384 * 2);  // 256 MiB
  float* cov  = (float*)carve(16ull * MS * 4);            // 16 MiB
  float* U    = (float*)carve(4ull * 16 * MS * 4);        // 64 MiB SYRK partials
  float* means = (float*)carve(8192 * 4);
  float* norm1 = (float*)carve(256);
  float* norm2 = (float*)carve(256);
  u16 *YH[2], *YL[2], *ZH[2], *ZL[2];
  for (int i = 0; i < 2; ++i) {
    YH[i] = (u16*)carve(8 * MS * 2); YL[i] = (u16*)carve(8 * MS * 2);
    ZH[i] = (u16*)carve(8 * MS * 2); ZL[i] = (u16*)carve(8 * MS * 2);
  }
  u16* Th = (u16*)carve(8 * MS * 2); u16* Tl = (u16*)carve(8 * MS * 2);
  u16* Ch = (u16*)carve(8 * MS * 2); u16* Cl = (u16*)carve(8 * MS * 2);
  u16* Ph = (u16*)carve(8 * MS * 2); u16* Pl = (u16*)carve(8 * MS * 2);
  float* Mb = (float*)carve(8 * MS * 4);
  float* partial = (float*)carve(4096 * 4);

  // 1) fp32 -> bf16 + means
  k_convert<<<8192, 256, 0, stream>>>(X0, X1, Xh, means);

  // 2) SYRK (K-split 4) + finish
  k_syrk<<<1024, 256, 0, stream>>>(Xh, U);
  k_covfin<<<2048, 256, 0, stream>>>(U, means, cov);

  // 3) NS #1 on target_cov (mats 8..15)
  k_frob<<<8, 256, 0, stream>>>(cov + 8 * MS, norm1);
  k_split<<<2048, 256, 0, stream>>>(cov + 8 * MS, norm1, YH[0], YL[0], ZH[0], ZL[0], 1);
  k_split<<<2048, 256, 0, stream>>>(cov, nullptr, Ch, Cl, nullptr, nullptr, 0);

  int cur = 0;
  for (int it = 0; it < NITER; ++it) {
    FJ tj = {ZH[cur], ZL[cur], YH[cur], YL[cur], Th, Tl, nullptr, nullptr, -0.5f, 1.5f};
    k_nsfused<<<512, 256, 0, stream>>>(tj, tj, 512);
    if (it < NITER - 1) {
      FJ yj = {YH[cur], YL[cur], Th, Tl, YH[1 - cur], YL[1 - cur], nullptr, nullptr, 1.f, 0.f};
      FJ zj = {Th, Tl, ZH[cur], ZL[cur], ZH[1 - cur], ZL[1 - cur], nullptr, nullptr, 1.f, 0.f};
      k_nsfused<<<1024, 256, 0, stream>>>(yj, zj, 512);
    } else {
      FJ yj = {YH[cur], YL[cur], Th, Tl, YH[1 - cur], YL[1 - cur], nullptr, nullptr, 1.f, 0.f};
      k_nsfused<<<512, 256, 0, stream>>>(yj, yj, 512);
    }
    cur ^= 1;
  }
  // Y_final (unit-scale sqrt of normalized target_cov) in YH[cur]/YL[cur]

  // 4) M = norm1 * (Y @ C @ Y)
  {
    FJ pj = {YH[cur], YL[cur], Ch, Cl, Ph, Pl, nullptr, nullptr, 1.f, 0.f};
    k_nsfused<<<512, 256, 0, stream>>>(pj, pj, 512);
    FJ mj = {Ph, Pl, YH[cur], YL[cur], nullptr, nullptr, Mb, norm1, 1.f, 0.f};
    k_nsfused<<<512, 256, 0, stream>>>(mj, mj, 512);
  }

  // 5) NS #2 on M; need diag(Y_final) only
  k_frob<<<8, 256, 0, stream>>>(Mb, norm2);
  k_split<<<2048, 256, 0, stream>>>(Mb, norm2, YH[0], YL[0], ZH[0], ZL[0], 1);
  cur = 0;
  for (int it = 0; it < NITER - 1; ++it) {  // 9 full iterations
    FJ tj = {ZH[cur], ZL[cur], YH[cur], YL[cur], Th, Tl, nullptr, nullptr, -0.5f, 1.5f};
    k_nsfused<<<512, 256, 0, stream>>>(tj, tj, 512);
    FJ yj = {YH[cur], YL[cur], Th, Tl, YH[1 - cur], YL[1 - cur], nullptr, nullptr, 1.f, 0.f};
    FJ zj = {Th, Tl, ZH[cur], ZL[cur], ZH[1 - cur], ZL[1 - cur], nullptr, nullptr, 1.f, 0.f};
    k_nsfused<<<1024, 256, 0, stream>>>(yj, zj, 512);
    cur ^= 1;
  }
  {  // final T; diag(Y9 @ T9) = diag(Y10)
    FJ tj = {ZH[cur], ZL[cur], YH[cur], YL[cur], Th, Tl, nullptr, nullptr, -0.5f, 1.5f};
    k_nsfused<<<512, 256, 0, stream>>>(tj, tj, 512);
  }

  // 6) loss
  k_diag<<<1024, 256, 0, stream>>>(YH[cur], YL[cur], Th, Tl, cov, norm2, partial);
  k_final<<<1, 256, 0, stream>>>(partial, means, out);
}

// Round 4
// 768.498 us; speedup vs baseline: 3.4399x; 1.7162x over previous
//
#include <hip/hip_runtime.h>

// StyleLossW2 on MI355X. B=8, C=512, HW=16384. Output: 1 fp32 scalar.
// Round 4: loss needs only tr(sqrt(C@TC)) -- single NS trace-chain on
// G = C@TC replaces NS1 + sandwich + NS2 (identity: lambda(S C S) =
// lambda(C@TC), S = sqrt(TC)). Non-symmetric iterates handled by writing
// transposed outputs in the GEMM epilogue. SYRK uses symmetry (10/16 tiles).

typedef unsigned short u16;
typedef __bf16 bf16_t;
typedef bf16_t bf16x8 __attribute__((ext_vector_type(8)));
typedef float f32x4 __attribute__((ext_vector_type(4)));

#define EPSV 1e-4f
#define MS 262144   // 512*512

__device__ inline u16 f2b(float f) {
  bf16_t b = (bf16_t)f;
  return __builtin_bit_cast(u16, b);
}
__device__ inline float b2f(u16 u) {
  unsigned v = ((unsigned)u) << 16;
  return __builtin_bit_cast(float, v);
}

// ---------------- 2-phase double-buffered MFMA tile core --------------------
// (verified r2/r3: swizzled source + XOR'd ds_read -> 0 bank conflicts)
template <int FR, int LDA, int LDB, int SPS>
__device__ __forceinline__ void core2(const u16* A0, const u16* A1, const u16* A2,
                                      const u16* B0, const u16* B1, const u16* B2,
                                      int nsteps, u16* lds, f32x4 (&acc)[FR][FR],
                                      int wave, int lane) {
  const int TS = FR * 32 * 64;  // elems per staged tile
  const u16* As[3] = {A0, A1, A2};
  const u16* Bs[3] = {B0, B1, B2};
  int rr = lane & 15, g4 = lane >> 4, wm = wave >> 1, wn = wave & 1;
  int swz = (rr & 7) << 3;
#pragma unroll
  for (int it = 0; it < FR; ++it) {
    int chunk = it * 4 + wave;
    __builtin_amdgcn_global_load_lds(
        (const __attribute__((address_space(1))) unsigned int*)(A0 + (size_t)(chunk * 8) * LDA),
        (__attribute__((address_space(3))) unsigned int*)&lds[chunk * 512], 16, 0, 0);
    __builtin_amdgcn_global_load_lds(
        (const __attribute__((address_space(1))) unsigned int*)(B0 + (size_t)(chunk * 8) * LDB),
        (__attribute__((address_space(3))) unsigned int*)&lds[TS + chunk * 512], 16, 0, 0);
  }
  __syncthreads();
  int buf = 0;
  for (int ks = 0; ks < nsteps; ++ks) {
    if (ks + 1 < nsteps) {
      int kn = ks + 1;
      int seg = kn / SPS;
      int k0 = (kn % SPS) * 64;
      const u16* A = As[seg];
      const u16* B = Bs[seg];
      u16* dst = lds + (buf ^ 1) * 2 * TS;
#pragma unroll
      for (int it = 0; it < FR; ++it) {
        int chunk = it * 4 + wave;
        __builtin_amdgcn_global_load_lds(
            (const __attribute__((address_space(1))) unsigned int*)(A + (size_t)(chunk * 8) * LDA + k0),
            (__attribute__((address_space(3))) unsigned int*)&dst[chunk * 512], 16, 0, 0);
        __builtin_amdgcn_global_load_lds(
            (const __attribute__((address_space(1))) unsigned int*)(B + (size_t)(chunk * 8) * LDB + k0),
            (__attribute__((address_space(3))) unsigned int*)&dst[TS + chunk * 512], 16, 0, 0);
      }
    }
    const u16* lb = lds + buf * 2 * TS;
#pragma unroll
    for (int kk = 0; kk < 2; ++kk) {
      int ko = (kk * 32 + g4 * 8) ^ swz;
      bf16x8 af[FR], bv[FR];
#pragma unroll
      for (int m = 0; m < FR; ++m)
        af[m] = *(const bf16x8*)&lb[(wm * FR * 16 + m * 16 + rr) * 64 + ko];
#pragma unroll
      for (int n = 0; n < FR; ++n)
        bv[n] = *(const bf16x8*)&lb[TS + (wn * FR * 16 + n * 16 + rr) * 64 + ko];
#pragma unroll
      for (int m = 0; m < FR; ++m)
#pragma unroll
        for (int n = 0; n < FR; ++n)
          acc[m][n] = __builtin_amdgcn_mfma_f32_16x16x32_bf16(af[m], bv[n],
                                                              acc[m][n], 0, 0, 0);
    }
    __syncthreads();
    buf ^= 1;
  }
}

// ---------------- convert fp32 -> bf16 (16B stores), per-row means ----------
__global__ __launch_bounds__(256) void k_convert(const float* __restrict__ X0,
                                                 const float* __restrict__ X1,
                                                 u16* __restrict__ Xh,
                                                 float* __restrict__ means) {
  int r = blockIdx.x;
  int tid = threadIdx.x;
  const float* src = (r < 4096) ? X0 : X1;
  size_t off = (size_t)(r & 4095) * 16384;
  const float4* s4 = (const float4*)(src + off);
  u16* dst = Xh + (size_t)r * 16384;
  float sum = 0.0f;
#pragma unroll
  for (int i = 0; i < 8; ++i) {
    int p = i * 256 + tid;
    float4 a = s4[p * 2];
    float4 b = s4[p * 2 + 1];
    sum += a.x + a.y + a.z + a.w + b.x + b.y + b.z + b.w;
    ushort4 u0, u1;
    u0.x = f2b(a.x); u0.y = f2b(a.y); u0.z = f2b(a.z); u0.w = f2b(a.w);
    u1.x = f2b(b.x); u1.y = f2b(b.y); u1.z = f2b(b.z); u1.w = f2b(b.w);
    ((ushort4*)dst)[p * 2] = u0;
    ((ushort4*)dst)[p * 2 + 1] = u1;
  }
  for (int o = 32; o; o >>= 1) sum += __shfl_down(sum, o);
  __shared__ float red[4];
  if ((tid & 63) == 0) red[tid >> 6] = sum;
  __syncthreads();
  if (tid == 0) means[r] = (red[0] + red[1] + red[2] + red[3]) * (1.0f / 16384.0f);
}

// ---------------- SYRK: 640 jobs = 16 mats x 10 sym-tiles x 4 K-quarters ----
__global__ __launch_bounds__(256) void k_syrk(const u16* __restrict__ Xh,
                                              float* __restrict__ covP) {
  const int TIv[10] = {0, 0, 0, 0, 1, 1, 1, 2, 2, 3};
  const int TJv[10] = {0, 1, 2, 3, 1, 2, 3, 2, 3, 3};
  int b = blockIdx.x;
  int sid = (b & 7) * 80 + (b >> 3);  // 640 = 8 * 80, bijective XCD swizzle
  int mat = sid / 40, rem = sid % 40;
  int t = rem >> 2, q = rem & 3;
  int ti = TIv[t], tj = TJv[t];
  int tid = threadIdx.x, wave = tid >> 6, lane = tid & 63;
  __shared__ u16 lds[2 * 2 * 128 * 64];  // 64 KB
  f32x4 acc[4][4] = {};
  int srow = lane >> 3;
  int scol = ((lane & 7) * 8) ^ (srow << 3);
  const u16* base = Xh + (size_t)mat * 512 * 16384 + (size_t)q * 4096;
  const u16* Ab = base + (size_t)(ti * 128 + srow) * 16384 + scol;
  const u16* Bb = base + (size_t)(tj * 128 + srow) * 16384 + scol;
  core2<4, 16384, 16384, 64>(Ab, Ab, Ab, Bb, Bb, Bb, 64, lds, acc, wave, lane);
  int wm = wave >> 1, wn = wave & 1, rr = lane & 15, g4 = lane >> 4;
  float* out = covP + ((size_t)q * 16 + mat) * MS;
#pragma unroll
  for (int m = 0; m < 4; ++m)
#pragma unroll
    for (int n = 0; n < 4; ++n) {
      int rowb = ti * 128 + wm * 64 + m * 16 + g4 * 4;
      int col = tj * 128 + wn * 64 + n * 16 + rr;
      float v0 = acc[m][n][0], v1 = acc[m][n][1], v2 = acc[m][n][2], v3 = acc[m][n][3];
      out[(size_t)(rowb + 0) * 512 + col] = v0;
      out[(size_t)(rowb + 1) * 512 + col] = v1;
      out[(size_t)(rowb + 2) * 512 + col] = v2;
      out[(size_t)(rowb + 3) * 512 + col] = v3;
      if (ti != tj) {
        float4 tv = {v0, v1, v2, v3};
        *(float4*)&out[(size_t)col * 512 + rowb] = tv;
      }
    }
}

// ---------------- cov finish: sum 4 K-quarters, /HW - mean outer + eps I ----
__global__ __launch_bounds__(256) void k_covfin(const float* __restrict__ covP,
                                                const float* __restrict__ means,
                                                float* __restrict__ cov) {
  const int NF4 = 16 * MS / 4;
  const float4* P0 = (const float4*)covP;
  const float4* P1 = P0 + NF4;
  const float4* P2 = P1 + NF4;
  const float4* P3 = P2 + NF4;
  for (int i4 = blockIdx.x * 256 + threadIdx.x; i4 < NF4; i4 += gridDim.x * 256) {
    float4 a = P0[i4], b = P1[i4], c = P2[i4], d = P3[i4];
    int mat = i4 >> 16;
    int r = (i4 >> 7) & 511;
    int cb = (i4 & 127) * 4;
    float mr = means[mat * 512 + r];
    float v[4] = {a.x + b.x + c.x + d.x, a.y + b.y + c.y + d.y,
                  a.z + b.z + c.z + d.z, a.w + b.w + c.w + d.w};
    float4 o;
    float* po = &o.x;
#pragma unroll
    for (int t = 0; t < 4; ++t) {
      float vv = v[t] * (1.0f / 16384.0f) - mr * means[mat * 512 + cb + t];
      if (r == cb + t) vv += EPSV;
      po[t] = vv;
    }
    ((float4*)cov)[i4] = o;
  }
}

// ---------------- hi/lo split of C (mats 0-7) and TC (mats 8-15) ------------
__global__ __launch_bounds__(256) void k_splitCov(const float* __restrict__ cov,
                                                  u16* __restrict__ Ch, u16* __restrict__ Cl,
                                                  u16* __restrict__ TCh, u16* __restrict__ TCl) {
  const int N4 = 16 * MS / 4;
  for (int i4 = blockIdx.x * 256 + threadIdx.x; i4 < N4; i4 += gridDim.x * 256) {
    float4 v = ((const float4*)cov)[i4];
    int half = i4 >> 19;          // 0: C, 1: TC
    int loc4 = i4 & 524287;
    const float* pv = &v.x;
    ushort4 h, l;
    unsigned short* ph = &h.x;
    unsigned short* pl = &l.x;
#pragma unroll
    for (int t = 0; t < 4; ++t) {
      u16 hh = f2b(pv[t]);
      ph[t] = hh;
      pl[t] = f2b(pv[t] - b2f(hh));
    }
    ((ushort4*)(half ? TCh : Ch))[loc4] = h;
    ((ushort4*)(half ? TCl : Cl))[loc4] = l;
  }
}

// ---------------- generic NS GEMM with optional transposed output -----------
struct GJ {
  const u16 *Ah, *Al, *Bh, *Bl;   // B arrays are transposed-layout operands
  u16 *oH, *oL, *oTH, *oTL;       // any may be null
  float* oF;                      // fp32 out (G)
  float c0, c1;                   // v = c0*acc + c1*(row==col)
};

__global__ __launch_bounds__(256) void k_gg(GJ p, GJ q, int split) {
  int sid = ((blockIdx.x & 7) * (gridDim.x >> 3)) + (blockIdx.x >> 3);
  const GJ j = (sid < split) ? p : q;
  int blk = (sid < split) ? sid : sid - split;
  int mat = blk >> 6, tile = blk & 63;
  int ti = tile >> 3, tj = tile & 7;
  int tid = threadIdx.x, wave = tid >> 6, lane = tid & 63;
  __shared__ u16 lds[2 * 2 * 64 * 64];  // 32 KB
  f32x4 acc[2][2] = {};
  int srow = lane >> 3;
  int scol = ((lane & 7) * 8) ^ (srow << 3);
  size_t mo = (size_t)mat * MS;
  size_t ao = mo + (size_t)(ti * 64 + srow) * 512 + scol;
  size_t bo = mo + (size_t)(tj * 64 + srow) * 512 + scol;
  const u16* A0 = j.Ah + ao;
  const u16* A2 = j.Al + ao;
  const u16* B0 = j.Bh + bo;
  const u16* B1 = j.Bl + bo;
  core2<2, 512, 512, 8>(A0, A0, A2, B0, B1, B0, 24, lds, acc, wave, lane);
  int wm = wave >> 1, wn = wave & 1, rr = lane & 15, g4 = lane >> 4;
#pragma unroll
  for (int m = 0; m < 2; ++m)
#pragma unroll
    for (int n = 0; n < 2; ++n) {
      int rowb = ti * 64 + wm * 32 + m * 16 + g4 * 4;
      int col = tj * 64 + wn * 32 + n * 16 + rr;
      float v[4];
      ushort4 h4, l4;
      unsigned short* ph = &h4.x;
      unsigned short* pl = &l4.x;
#pragma unroll
      for (int v4 = 0; v4 < 4; ++v4) {
        float vv = j.c0 * acc[m][n][v4] + ((rowb + v4) == col ? j.c1 : 0.0f);
        v[v4] = vv;
        u16 hh = f2b(vv);
        ph[v4] = hh;
        pl[v4] = f2b(vv - b2f(hh));
      }
      if (j.oF) {
#pragma unroll
        for (int v4 = 0; v4 < 4; ++v4)
          j.oF[mo + (size_t)(rowb + v4) * 512 + col] = v[v4];
      }
      if (j.oH) {
#pragma unroll
        for (int v4 = 0; v4 < 4; ++v4) {
          j.oH[mo + (size_t)(rowb + v4) * 512 + col] = ph[v4];
          j.oL[mo + (size_t)(rowb + v4) * 512 + col] = pl[v4];
        }
      }
      if (j.oTH) {  // transposed: out^T[col][rowb..rowb+3], packed 8B
        *(ushort4*)&j.oTH[mo + (size_t)col * 512 + rowb] = h4;
        *(ushort4*)&j.oTL[mo + (size_t)col * 512 + rowb] = l4;
      }
    }
}

// ---------------- Frobenius partials of G (64 chunks) -----------------------
__global__ __launch_bounds__(256) void k_frobP(const float* __restrict__ G,
                                               float* __restrict__ frobP) {
  int b = blockIdx.x;  // 64 = 8 mats x 8 chunks
  const float4* p = (const float4*)(G + (size_t)b * 32768);
  float s = 0.0f;
  for (int i = threadIdx.x; i < 8192; i += 256) {
    float4 v = p[i];
    s += v.x * v.x + v.y * v.y + v.z * v.z + v.w * v.w;
  }
  for (int o = 32; o; o >>= 1) s += __shfl_down(s, o);
  __shared__ float red[4];
  if ((threadIdx.x & 63) == 0) red[threadIdx.x >> 6] = s;
  __syncthreads();
  if (threadIdx.x == 0) frobP[b] = red[0] + red[1] + red[2] + red[3];
}

// ---------------- split G: X0=G/nu -> Y0,T0 (+ transposes), hi/lo -----------
__global__ __launch_bounds__(256) void k_split_g(const float* __restrict__ G,
                                                 const float* __restrict__ frobP,
                                                 u16* __restrict__ Yh, u16* __restrict__ Yl,
                                                 u16* __restrict__ Yth, u16* __restrict__ Ytl,
                                                 u16* __restrict__ Th, u16* __restrict__ Tl,
                                                 u16* __restrict__ Tth, u16* __restrict__ Ttl) {
  __shared__ float lds[64][65];
  int b = blockIdx.x;  // 512 = 8 mats x 64 tiles
  int mat = b >> 6, tile = b & 63;
  int tr = tile >> 3, tc = tile & 7;
  float ns = 0.0f;
#pragma unroll
  for (int i = 0; i < 8; ++i) ns += frobP[mat * 8 + i];
  float inv = 1.0f / sqrtf(ns);
  const float* src = G + (size_t)mat * MS + (size_t)(tr * 64) * 512 + tc * 64;
  size_t mo = (size_t)mat * MS;
  for (int i = threadIdx.x; i < 4096; i += 256) {
    int r = i >> 6, c = i & 63;
    float v = src[(size_t)r * 512 + c];
    lds[r][c] = v;
    int gr = tr * 64 + r, gc = tc * 64 + c;
    float x = v * inv;
    size_t idx = mo + (size_t)gr * 512 + gc;
    u16 h = f2b(x);
    Yh[idx] = h; Yl[idx] = f2b(x - b2f(h));
    float tv = (gr == gc ? 1.5f : 0.0f) - 0.5f * x;
    u16 th = f2b(tv);
    Th[idx] = th; Tl[idx] = f2b(tv - b2f(th));
  }
  __syncthreads();
  for (int i = threadIdx.x; i < 4096; i += 256) {
    int r = i >> 6, c = i & 63;
    float v = lds[c][r];  // G[tr*64+c][tc*64+r]
    int gr = tc * 64 + r, gc = tr * 64 + c;  // position in transposed arrays
    float x = v * inv;
    size_t idx = mo + (size_t)gr * 512 + gc;
    u16 h = f2b(x);
    Yth[idx] = h; Ytl[idx] = f2b(x - b2f(h));
    float tv = (gr == gc ? 1.5f : 0.0f) - 0.5f * x;
    u16 th = f2b(tv);
    Tth[idx] = th; Ttl[idx] = f2b(tv - b2f(th));
  }
}

// ---------------- trace dot: sum (Y9T .* T9) per chunk ----------------------
__global__ __launch_bounds__(256) void k_dot(const u16* __restrict__ Yth,
                                             const u16* __restrict__ Ytl,
                                             const u16* __restrict__ Th,
                                             const u16* __restrict__ Tl,
                                             float* __restrict__ dotp) {
  int b = blockIdx.x;  // 64 = 8 mats x 8 chunks
  size_t off = (size_t)b * 32768;
  float s = 0.0f;
  for (int i = threadIdx.x; i < 8192; i += 256) {
    ushort4 yh = ((const ushort4*)(Yth + off))[i];
    ushort4 yl = ((const ushort4*)(Ytl + off))[i];
    ushort4 th = ((const ushort4*)(Th + off))[i];
    ushort4 tl = ((const ushort4*)(Tl + off))[i];
    s += (b2f(yh.x) + b2f(yl.x)) * (b2f(th.x) + b2f(tl.x));
    s += (b2f(yh.y) + b2f(yl.y)) * (b2f(th.y) + b2f(tl.y));
    s += (b2f(yh.z) + b2f(yl.z)) * (b2f(th.z) + b2f(tl.z));
    s += (b2f(yh.w) + b2f(yl.w)) * (b2f(th.w) + b2f(tl.w));
  }
  for (int o = 32; o; o >>= 1) s += __shfl_down(s, o);
  __shared__ float red[4];
  if ((threadIdx.x & 63) == 0) red[threadIdx.x >> 6] = s;
  __syncthreads();
  if (threadIdx.x == 0) dotp[b] = red[0] + red[1] + red[2] + red[3];
}

// ---------------- final scalar --------------------------------------------
__global__ __launch_bounds__(256) void k_final(const float* __restrict__ dotp,
                                               const float* __restrict__ frobP,
                                               const float* __restrict__ cov,
                                               const float* __restrict__ means,
                                               float* __restrict__ out) {
  float s = 0.0f;
  for (int i = threadIdx.x; i < 4096; i += 256) {
    float dm = means[i] - means[4096 + i];
    s += dm * dm;
  }
  for (int i = threadIdx.x; i < 8192; i += 256) {
    int mat = i >> 9, r = i & 511;
    s += cov[(size_t)mat * MS + (size_t)r * 513];
  }
  if (threadIdx.x < 8) {
    int m = threadIdx.x;
    float ns = 0.0f;
#pragma unroll
    for (int i = 0; i < 8; ++i) ns += frobP[m * 8 + i];
    float inv = 1.0f / sqrtf(ns);     // identical fp sequence to k_split_g
    float sroot = 1.0f / sqrtf(inv);  // = sqrt(nu) with exact compensation
    float tr = 0.0f;
#pragma unroll
    for (int i = 0; i < 8; ++i) tr += dotp[m * 8 + i];
    s -= 2.0f * sroot * tr;
  }
  for (int o = 32; o; o >>= 1) s += __shfl_down(s, o);
  __shared__ float red[4];
  if ((threadIdx.x & 63) == 0) red[threadIdx.x >> 6] = s;
  __syncthreads();
  if (threadIdx.x == 0)
    out[0] = (red[0] + red[1] + red[2] + red[3]) * (1.0f / 4096.0f);
}

// ---------------- host ------------------------------------------------------
extern "C" void kernel_launch(void* const* d_in, const int* in_sizes, int n_in,
                              void* d_out, int out_size, void* d_ws, size_t ws_size,
                              hipStream_t stream) {
  (void)in_sizes; (void)n_in; (void)out_size; (void)ws_size;
  const float* X0 = (const float*)d_in[0];
  const float* X1 = (const float*)d_in[1];
  float* out = (float*)d_out;

  char* w = (char*)d_ws;
  auto carve = [&](size_t bytes) -> void* {
    void* r = (void*)w;
    w += (bytes + 255) & ~(size_t)255;
    return r;
  };
  u16*   Xh    = (u16*)carve(2ull * 8 * 512 * 16384 * 2);  // 256 MiB
  float* covP  = (float*)carve(4ull * 16 * MS * 4);        // 64 MiB
  float* cov   = (float*)carve(16ull * MS * 4);            // 16 MiB
  u16* Ch  = (u16*)carve(8 * MS * 2); u16* Cl  = (u16*)carve(8 * MS * 2);
  u16* TCh = (u16*)carve(8 * MS * 2); u16* TCl = (u16*)carve(8 * MS * 2);
  float* G = (float*)carve(8ull * MS * 4);                 // 8 MiB
  // sets: {h, l, th, tl} x 8 mats
  u16* YS[2][4]; u16* ZS[2][4]; u16* TS[2][4];
  for (int i = 0; i < 2; ++i)
    for (int a = 0; a < 4; ++a) {
      YS[i][a] = (u16*)carve(8 * MS * 2);
      ZS[i][a] = (u16*)carve(8 * MS * 2);
      TS[i][a] = (u16*)carve(8 * MS * 2);
    }
  float* means = (float*)carve(8192 * 4);
  float* frobP = (float*)carve(64 * 4);
  float* dotp  = (float*)carve(64 * 4);

  // 1) fp32 -> bf16 + means
  k_convert<<<8192, 256, 0, stream>>>(X0, X1, Xh, means);

  // 2) SYRK (symmetric tiles, K-split 4) + finish -> cov (C mats 0-7, TC 8-15)
  k_syrk<<<640, 256, 0, stream>>>(Xh, covP);
  k_covfin<<<2048, 256, 0, stream>>>(covP, means, cov);

  // 3) hi/lo split of C and TC
  k_splitCov<<<2048, 256, 0, stream>>>(cov, Ch, Cl, TCh, TCl);

  // 4) G = C @ TC  (TC symmetric -> B-layout = TC itself)
  {
    GJ gj = {Ch, Cl, TCh, TCl, nullptr, nullptr, nullptr, nullptr, G, 1.0f, 0.0f};
    k_gg<<<512, 256, 0, stream>>>(gj, gj, 512);
  }
  k_frobP<<<64, 256, 0, stream>>>(G, frobP);

  // 5) X0 = G/nu: Y0 = X0, T0 = 1.5I - 0.5 X0, with transposes
  k_split_g<<<512, 256, 0, stream>>>(G, frobP,
                                     YS[0][0], YS[0][1], YS[0][2], YS[0][3],
                                     TS[0][0], TS[0][1], TS[0][2], TS[0][3]);

  // 6) NS trace-chain on G.  Z1 = T0 (alias).  iters produce Y_{k+1}, Z_{k+1}.
  // iter 0: Y1 = Y0 @ T0
  {
    GJ yj = {YS[0][0], YS[0][1], TS[0][2], TS[0][3],
             YS[1][0], YS[1][1], YS[1][2], YS[1][3], nullptr, 1.0f, 0.0f};
    k_gg<<<512, 256, 0, stream>>>(yj, yj, 512);
  }
  u16** Zk = TS[0];  // Z1 = T0
  for (int k = 1; k <= 8; ++k) {
    u16** Yk = YS[k & 1];
    u16** Tk = TS[k & 1];
    u16** Yn = YS[(k + 1) & 1];
    u16** Zn = ZS[(k + 1) & 1];
    // T_k = 1.5I - 0.5 * Z_k @ Y_k   (B = Yk^T)
    GJ tj = {Zk[0], Zk[1], Yk[2], Yk[3],
             Tk[0], Tk[1], Tk[2], Tk[3], nullptr, -0.5f, 1.5f};
    k_gg<<<512, 256, 0, stream>>>(tj, tj, 512);
    // Y_{k+1} = Y_k @ T_k (B = Tk^T);  Z_{k+1} = T_k @ Z_k (B = Zk^T)
    GJ yj = {Yk[0], Yk[1], Tk[2], Tk[3],
             Yn[0], Yn[1], Yn[2], Yn[3], nullptr, 1.0f, 0.0f};
    GJ zj = {Tk[0], Tk[1], Zk[2], Zk[3],
             Zn[0], Zn[1], Zn[2], Zn[3], nullptr, 1.0f, 0.0f};
    if (k == 8) {               // only Y9^T and Z9 needed downstream
      yj.oH = nullptr; yj.oL = nullptr;
      zj.oTH = nullptr; zj.oTL = nullptr;
    }
    k_gg<<<1024, 256, 0, stream>>>(yj, zj, 512);
    Zk = Zn;
  }
  // T9 = 1.5I - 0.5 * Z9 @ Y9  (B = Y9^T); normal layout only
  {
    u16** Y9 = YS[1];
    u16** T9 = TS[1];
    GJ tj = {Zk[0], Zk[1], Y9[2], Y9[3],
             T9[0], T9[1], nullptr, nullptr, nullptr, -0.5f, 1.5f};
    k_gg<<<512, 256, 0, stream>>>(tj, tj, 512);
  }

  // 7) trace = <Y9^T, T9>;  loss = mean_diff + (trC + trTC - 2*sqrt(nu)*trace)/4096
  k_dot<<<64, 256, 0, stream>>>(YS[1][2], YS[1][3], TS[1][0], TS[1][1], dotp);
  k_final<<<1, 256, 0, stream>>>(dotp, frobP, cov, means, out);
}

// Round 5
// 553.360 us; speedup vs baseline: 4.7773x; 1.3888x over previous
//
#include <hip/hip_runtime.h>

// StyleLossW2 on MI355X. B=8, C=512, HW=16384. Output: 1 fp32 scalar.
// Round 5: spectral normalization of G = C@TC via moment ratio tr(G^2)/tr(G)
// (*1.35 safety) -> 5 NS iterations instead of 10 (launches 19 -> 10).
// Wave-per-row convert (no barriers, 16B stores). Fused covfin + hi/lo split.

typedef unsigned short u16;
typedef __bf16 bf16_t;
typedef bf16_t bf16x8 __attribute__((ext_vector_type(8)));
typedef float f32x4 __attribute__((ext_vector_type(4)));

#define EPSV 1e-4f
#define MS 262144   // 512*512

__device__ inline u16 f2b(float f) {
  bf16_t b = (bf16_t)f;
  return __builtin_bit_cast(u16, b);
}
__device__ inline float b2f(u16 u) {
  unsigned v = ((unsigned)u) << 16;
  return __builtin_bit_cast(float, v);
}

// ---------------- 2-phase double-buffered MFMA tile core --------------------
// (verified r2-r4: swizzled source + XOR'd ds_read -> 0 bank conflicts)
template <int FR, int LDA, int LDB, int SPS>
__device__ __forceinline__ void core2(const u16* A0, const u16* A1, const u16* A2,
                                      const u16* B0, const u16* B1, const u16* B2,
                                      int nsteps, u16* lds, f32x4 (&acc)[FR][FR],
                                      int wave, int lane) {
  const int TS = FR * 32 * 64;  // elems per staged tile
  const u16* As[3] = {A0, A1, A2};
  const u16* Bs[3] = {B0, B1, B2};
  int rr = lane & 15, g4 = lane >> 4, wm = wave >> 1, wn = wave & 1;
  int swz = (rr & 7) << 3;
#pragma unroll
  for (int it = 0; it < FR; ++it) {
    int chunk = it * 4 + wave;
    __builtin_amdgcn_global_load_lds(
        (const __attribute__((address_space(1))) unsigned int*)(A0 + (size_t)(chunk * 8) * LDA),
        (__attribute__((address_space(3))) unsigned int*)&lds[chunk * 512], 16, 0, 0);
    __builtin_amdgcn_global_load_lds(
        (const __attribute__((address_space(1))) unsigned int*)(B0 + (size_t)(chunk * 8) * LDB),
        (__attribute__((address_space(3))) unsigned int*)&lds[TS + chunk * 512], 16, 0, 0);
  }
  __syncthreads();
  int buf = 0;
  for (int ks = 0; ks < nsteps; ++ks) {
    if (ks + 1 < nsteps) {
      int kn = ks + 1;
      int seg = kn / SPS;
      int k0 = (kn % SPS) * 64;
      const u16* A = As[seg];
      const u16* B = Bs[seg];
      u16* dst = lds + (buf ^ 1) * 2 * TS;
#pragma unroll
      for (int it = 0; it < FR; ++it) {
        int chunk = it * 4 + wave;
        __builtin_amdgcn_global_load_lds(
            (const __attribute__((address_space(1))) unsigned int*)(A + (size_t)(chunk * 8) * LDA + k0),
            (__attribute__((address_space(3))) unsigned int*)&dst[chunk * 512], 16, 0, 0);
        __builtin_amdgcn_global_load_lds(
            (const __attribute__((address_space(1))) unsigned int*)(B + (size_t)(chunk * 8) * LDB + k0),
            (__attribute__((address_space(3))) unsigned int*)&dst[TS + chunk * 512], 16, 0, 0);
      }
    }
    const u16* lb = lds + buf * 2 * TS;
#pragma unroll
    for (int kk = 0; kk < 2; ++kk) {
      int ko = (kk * 32 + g4 * 8) ^ swz;
      bf16x8 af[FR], bv[FR];
#pragma unroll
      for (int m = 0; m < FR; ++m)
        af[m] = *(const bf16x8*)&lb[(wm * FR * 16 + m * 16 + rr) * 64 + ko];
#pragma unroll
      for (int n = 0; n < FR; ++n)
        bv[n] = *(const bf16x8*)&lb[TS + (wn * FR * 16 + n * 16 + rr) * 64 + ko];
#pragma unroll
      for (int m = 0; m < FR; ++m)
#pragma unroll
        for (int n = 0; n < FR; ++n)
          acc[m][n] = __builtin_amdgcn_mfma_f32_16x16x32_bf16(af[m], bv[n],
                                                              acc[m][n], 0, 0, 0);
    }
    __syncthreads();
    buf ^= 1;
  }
}

// ---------------- convert fp32 -> bf16, wave-per-row, no barriers -----------
__global__ __launch_bounds__(256) void k_convert(const float* __restrict__ X0,
                                                 const float* __restrict__ X1,
                                                 u16* __restrict__ Xh,
                                                 float* __restrict__ means) {
  int wave = threadIdx.x >> 6, lane = threadIdx.x & 63;
  int r = blockIdx.x * 4 + wave;
  const float* src = (r < 4096) ? X0 : X1;
  size_t off = (size_t)(r & 4095) * 16384;
  const float4* s4 = (const float4*)(src + off);
  uint4* dst = (uint4*)(Xh + (size_t)r * 16384);
  float sum = 0.0f;
#pragma unroll 8
  for (int i = 0; i < 32; ++i) {
    int c = i * 64 + lane;
    float4 a = s4[2 * c];
    float4 b = s4[2 * c + 1];
    sum += a.x + a.y + a.z + a.w + b.x + b.y + b.z + b.w;
    uint4 o;
    o.x = (unsigned)f2b(a.x) | ((unsigned)f2b(a.y) << 16);
    o.y = (unsigned)f2b(a.z) | ((unsigned)f2b(a.w) << 16);
    o.z = (unsigned)f2b(b.x) | ((unsigned)f2b(b.y) << 16);
    o.w = (unsigned)f2b(b.z) | ((unsigned)f2b(b.w) << 16);
    dst[c] = o;
  }
  for (int o = 32; o; o >>= 1) sum += __shfl_down(sum, o);
  if (lane == 0) means[r] = sum * (1.0f / 16384.0f);
}

// ---------------- SYRK: 640 jobs = 16 mats x 10 sym-tiles x 4 K-quarters ----
__global__ __launch_bounds__(256) void k_syrk(const u16* __restrict__ Xh,
                                              float* __restrict__ covP) {
  const int TIv[10] = {0, 0, 0, 0, 1, 1, 1, 2, 2, 3};
  const int TJv[10] = {0, 1, 2, 3, 1, 2, 3, 2, 3, 3};
  int b = blockIdx.x;
  int sid = (b & 7) * 80 + (b >> 3);  // bijective XCD swizzle
  int mat = sid / 40, rem = sid % 40;
  int t = rem >> 2, q = rem & 3;
  int ti = TIv[t], tj = TJv[t];
  int tid = threadIdx.x, wave = tid >> 6, lane = tid & 63;
  __shared__ u16 lds[2 * 2 * 128 * 64];  // 64 KB
  f32x4 acc[4][4] = {};
  int srow = lane >> 3;
  int scol = ((lane & 7) * 8) ^ (srow << 3);
  const u16* base = Xh + (size_t)mat * 512 * 16384 + (size_t)q * 4096;
  const u16* Ab = base + (size_t)(ti * 128 + srow) * 16384 + scol;
  const u16* Bb = base + (size_t)(tj * 128 + srow) * 16384 + scol;
  core2<4, 16384, 16384, 64>(Ab, Ab, Ab, Bb, Bb, Bb, 64, lds, acc, wave, lane);
  int wm = wave >> 1, wn = wave & 1, rr = lane & 15, g4 = lane >> 4;
  float* out = covP + ((size_t)q * 16 + mat) * MS;
#pragma unroll
  for (int m = 0; m < 4; ++m)
#pragma unroll
    for (int n = 0; n < 4; ++n) {
      int rowb = ti * 128 + wm * 64 + m * 16 + g4 * 4;
      int col = tj * 128 + wn * 64 + n * 16 + rr;
      float v0 = acc[m][n][0], v1 = acc[m][n][1], v2 = acc[m][n][2], v3 = acc[m][n][3];
      out[(size_t)(rowb + 0) * 512 + col] = v0;
      out[(size_t)(rowb + 1) * 512 + col] = v1;
      out[(size_t)(rowb + 2) * 512 + col] = v2;
      out[(size_t)(rowb + 3) * 512 + col] = v3;
      if (ti != tj) {
        float4 tv = {v0, v1, v2, v3};
        *(float4*)&out[(size_t)col * 512 + rowb] = tv;
      }
    }
}

// ---- cov finish fused: sum K-quarters, /HW - mean outer + eps I,
//      write hi/lo bf16 (C mats 0-7, TC mats 8-15) + fp32 diag --------------
__global__ __launch_bounds__(256) void k_covfin2(const float* __restrict__ covP,
                                                 const float* __restrict__ means,
                                                 float* __restrict__ covdiag,
                                                 u16* __restrict__ Ch, u16* __restrict__ Cl,
                                                 u16* __restrict__ TCh, u16* __restrict__ TCl) {
  const int NF4 = 16 * MS / 4;  // 1048576
  const float4* P0 = (const float4*)covP;
  const float4* P1 = P0 + NF4;
  const float4* P2 = P1 + NF4;
  const float4* P3 = P2 + NF4;
  for (int i4 = blockIdx.x * 256 + threadIdx.x; i4 < NF4; i4 += gridDim.x * 256) {
    float4 a = P0[i4], b = P1[i4], c = P2[i4], d = P3[i4];
    int mat = i4 >> 16;
    int r = (i4 >> 7) & 511;
    int cb = (i4 & 127) * 4;
    float mr = means[mat * 512 + r];
    float v[4] = {a.x + b.x + c.x + d.x, a.y + b.y + c.y + d.y,
                  a.z + b.z + c.z + d.z, a.w + b.w + c.w + d.w};
    ushort4 h4, l4;
    unsigned short* ph = &h4.x;
    unsigned short* pl = &l4.x;
#pragma unroll
    for (int t = 0; t < 4; ++t) {
      float vv = v[t] * (1.0f / 16384.0f) - mr * means[mat * 512 + cb + t];
      if (r == cb + t) {
        vv += EPSV;
        covdiag[mat * 512 + r] = vv;
      }
      u16 hh = f2b(vv);
      ph[t] = hh;
      pl[t] = f2b(vv - b2f(hh));
    }
    int half = (mat >= 8);
    int loc4 = i4 - half * (NF4 / 2);
    ((ushort4*)(half ? TCh : Ch))[loc4] = h4;
    ((ushort4*)(half ? TCl : Cl))[loc4] = l4;
  }
}

// ---------------- generic NS GEMM with optional transposed output -----------
struct GJ {
  const u16 *Ah, *Al, *Bh, *Bl;   // B arrays are transposed-layout operands
  u16 *oH, *oL, *oTH, *oTL;       // any may be null
  float* oF;                      // fp32 out (G)
  float c0, c1;                   // v = c0*acc + c1*(row==col)
};

__global__ __launch_bounds__(256) void k_gg(GJ p, GJ q, int split) {
  int sid = ((blockIdx.x & 7) * (gridDim.x >> 3)) + (blockIdx.x >> 3);
  const GJ j = (sid < split) ? p : q;
  int blk = (sid < split) ? sid : sid - split;
  int mat = blk >> 6, tile = blk & 63;
  int ti = tile >> 3, tj = tile & 7;
  int tid = threadIdx.x, wave = tid >> 6, lane = tid & 63;
  __shared__ u16 lds[2 * 2 * 64 * 64];  // 32 KB
  f32x4 acc[2][2] = {};
  int srow = lane >> 3;
  int scol = ((lane & 7) * 8) ^ (srow << 3);
  size_t mo = (size_t)mat * MS;
  size_t ao = mo + (size_t)(ti * 64 + srow) * 512 + scol;
  size_t bo = mo + (size_t)(tj * 64 + srow) * 512 + scol;
  const u16* A0 = j.Ah + ao;
  const u16* A2 = j.Al + ao;
  const u16* B0 = j.Bh + bo;
  const u16* B1 = j.Bl + bo;
  core2<2, 512, 512, 8>(A0, A0, A2, B0, B1, B0, 24, lds, acc, wave, lane);
  int wm = wave >> 1, wn = wave & 1, rr = lane & 15, g4 = lane >> 4;
#pragma unroll
  for (int m = 0; m < 2; ++m)
#pragma unroll
    for (int n = 0; n < 2; ++n) {
      int rowb = ti * 64 + wm * 32 + m * 16 + g4 * 4;
      int col = tj * 64 + wn * 32 + n * 16 + rr;
      float v[4];
      ushort4 h4, l4;
      unsigned short* ph = &h4.x;
      unsigned short* pl = &l4.x;
#pragma unroll
      for (int v4 = 0; v4 < 4; ++v4) {
        float vv = j.c0 * acc[m][n][v4] + ((rowb + v4) == col ? j.c1 : 0.0f);
        v[v4] = vv;
        u16 hh = f2b(vv);
        ph[v4] = hh;
        pl[v4] = f2b(vv - b2f(hh));
      }
      if (j.oF) {
#pragma unroll
        for (int v4 = 0; v4 < 4; ++v4)
          j.oF[mo + (size_t)(rowb + v4) * 512 + col] = v[v4];
      }
      if (j.oH) {
#pragma unroll
        for (int v4 = 0; v4 < 4; ++v4) {
          j.oH[mo + (size_t)(rowb + v4) * 512 + col] = ph[v4];
          j.oL[mo + (size_t)(rowb + v4) * 512 + col] = pl[v4];
        }
      }
      if (j.oTH) {
        *(ushort4*)&j.oTH[mo + (size_t)col * 512 + rowb] = h4;
        *(ushort4*)&j.oTL[mo + (size_t)col * 512 + rowb] = l4;
      }
    }
}

// ---- trace moments: tr1P = partial tr(G), tr2P = partial tr(G^2) -----------
// 64 blocks = 8 mats x 8 row-blocks; tr(G^2) = sum_ij G[i][j]*G[j][i].
__global__ __launch_bounds__(256) void k_trmom(const float* __restrict__ G,
                                               float* __restrict__ tr1P,
                                               float* __restrict__ tr2P) {
  int b = blockIdx.x;
  int mat = b >> 3, rb = b & 7;
  const float* Gm = G + (size_t)mat * MS;
  __shared__ float bt[64][65];
  int tid = threadIdx.x;
  float s2 = 0.0f, s1 = 0.0f;
  for (int tc = 0; tc < 8; ++tc) {
    for (int l = tid; l < 1024; l += 256) {
      int rr = l >> 4, c4 = (l & 15) * 4;
      float4 v = *(const float4*)&Gm[(size_t)(tc * 64 + rr) * 512 + rb * 64 + c4];
      bt[rr][c4 + 0] = v.x; bt[rr][c4 + 1] = v.y;
      bt[rr][c4 + 2] = v.z; bt[rr][c4 + 3] = v.w;
    }
    __syncthreads();
    if (tc == rb && tid < 64) s1 += bt[tid][tid];
    int ra = tid >> 2, seg = tid & 3;
    const float* arow = &Gm[(size_t)(rb * 64 + ra) * 512 + tc * 64 + seg * 16];
#pragma unroll
    for (int u = 0; u < 4; ++u) {
      float4 a = *(const float4*)&arow[u * 4];
      int c0 = seg * 16 + u * 4;
      s2 += a.x * bt[c0 + 0][ra] + a.y * bt[c0 + 1][ra] +
            a.z * bt[c0 + 2][ra] + a.w * bt[c0 + 3][ra];
    }
    __syncthreads();
  }
  for (int o = 32; o; o >>= 1) {
    s2 += __shfl_down(s2, o);
    s1 += __shfl_down(s1, o);
  }
  __shared__ float r2[4], r1[4];
  if ((tid & 63) == 0) { r2[tid >> 6] = s2; r1[tid >> 6] = s1; }
  __syncthreads();
  if (tid == 0) {
    tr2P[b] = r2[0] + r2[1] + r2[2] + r2[3];
    tr1P[b] = r1[0] + r1[1] + r1[2] + r1[3];
  }
}

__device__ inline float nu_of(const float* tr1P, const float* tr2P, int mat) {
  float t1 = 0.0f, t2 = 0.0f;
#pragma unroll
  for (int i = 0; i < 8; ++i) { t1 += tr1P[mat * 8 + i]; t2 += tr2P[mat * 8 + i]; }
  return 1.35f * t2 / t1;  // 1.35 * tr(G^2)/tr(G) <= 1.35 * lmax
}

// ---------------- split G: X0=G/nu -> Y0,T0 (+ transposes), hi/lo -----------
__global__ __launch_bounds__(256) void k_split_g(const float* __restrict__ G,
                                                 const float* __restrict__ tr1P,
                                                 const float* __restrict__ tr2P,
                                                 u16* __restrict__ Yh, u16* __restrict__ Yl,
                                                 u16* __restrict__ Yth, u16* __restrict__ Ytl,
                                                 u16* __restrict__ Th, u16* __restrict__ Tl,
                                                 u16* __restrict__ Tth, u16* __restrict__ Ttl) {
  __shared__ float lds[64][65];
  int b = blockIdx.x;  // 512 = 8 mats x 64 tiles
  int mat = b >> 6, tile = b & 63;
  int tr = tile >> 3, tc = tile & 7;
  float inv = 1.0f / nu_of(tr1P, tr2P, mat);
  const float* src = G + (size_t)mat * MS + (size_t)(tr * 64) * 512 + tc * 64;
  size_t mo = (size_t)mat * MS;
  for (int i = threadIdx.x; i < 4096; i += 256) {
    int r = i >> 6, c = i & 63;
    float v = src[(size_t)r * 512 + c];
    lds[r][c] = v;
    int gr = tr * 64 + r, gc = tc * 64 + c;
    float x = v * inv;
    size_t idx = mo + (size_t)gr * 512 + gc;
    u16 h = f2b(x);
    Yh[idx] = h; Yl[idx] = f2b(x - b2f(h));
    float tv = (gr == gc ? 1.5f : 0.0f) - 0.5f * x;
    u16 th = f2b(tv);
    Th[idx] = th; Tl[idx] = f2b(tv - b2f(th));
  }
  __syncthreads();
  for (int i = threadIdx.x; i < 4096; i += 256) {
    int r = i >> 6, c = i & 63;
    float v = lds[c][r];
    int gr = tc * 64 + r, gc = tr * 64 + c;
    float x = v * inv;
    size_t idx = mo + (size_t)gr * 512 + gc;
    u16 h = f2b(x);
    Yth[idx] = h; Ytl[idx] = f2b(x - b2f(h));
    float tv = (gr == gc ? 1.5f : 0.0f) - 0.5f * x;
    u16 th = f2b(tv);
    Tth[idx] = th; Ttl[idx] = f2b(tv - b2f(th));
  }
}

// ---------------- trace dot: sum (Y4T .* T4) per chunk ----------------------
__global__ __launch_bounds__(256) void k_dot(const u16* __restrict__ Yth,
                                             const u16* __restrict__ Ytl,
                                             const u16* __restrict__ Th,
                                             const u16* __restrict__ Tl,
                                             float* __restrict__ dotp) {
  int b = blockIdx.x;  // 64 = 8 mats x 8 chunks
  size_t off = (size_t)b * 32768;
  float s = 0.0f;
  for (int i = threadIdx.x; i < 8192; i += 256) {
    ushort4 yh = ((const ushort4*)(Yth + off))[i];
    ushort4 yl = ((const ushort4*)(Ytl + off))[i];
    ushort4 th = ((const ushort4*)(Th + off))[i];
    ushort4 tl = ((const ushort4*)(Tl + off))[i];
    s += (b2f(yh.x) + b2f(yl.x)) * (b2f(th.x) + b2f(tl.x));
    s += (b2f(yh.y) + b2f(yl.y)) * (b2f(th.y) + b2f(tl.y));
    s += (b2f(yh.z) + b2f(yl.z)) * (b2f(th.z) + b2f(tl.z));
    s += (b2f(yh.w) + b2f(yl.w)) * (b2f(th.w) + b2f(tl.w));
  }
  for (int o = 32; o; o >>= 1) s += __shfl_down(s, o);
  __shared__ float red[4];
  if ((threadIdx.x & 63) == 0) red[threadIdx.x >> 6] = s;
  __syncthreads();
  if (threadIdx.x == 0) dotp[b] = red[0] + red[1] + red[2] + red[3];
}

// ---------------- final scalar ----------------------------------------------
__global__ __launch_bounds__(256) void k_final(const float* __restrict__ dotp,
                                               const float* __restrict__ tr1P,
                                               const float* __restrict__ tr2P,
                                               const float* __restrict__ covdiag,
                                               const float* __restrict__ means,
                                               float* __restrict__ out) {
  float s = 0.0f;
  for (int i = threadIdx.x; i < 4096; i += 256) {
    float dm = means[i] - means[4096 + i];
    s += dm * dm;
  }
  for (int i = threadIdx.x; i < 8192; i += 256) s += covdiag[i];
  if (threadIdx.x < 8) {
    int m = threadIdx.x;
    float nu = nu_of(tr1P, tr2P, m);
    float tr = 0.0f;
#pragma unroll
    for (int i = 0; i < 8; ++i) tr += dotp[m * 8 + i];
    s -= 2.0f * sqrtf(nu) * tr;
  }
  for (int o = 32; o; o >>= 1) s += __shfl_down(s, o);
  __shared__ float red[4];
  if ((threadIdx.x & 63) == 0) red[threadIdx.x >> 6] = s;
  __syncthreads();
  if (threadIdx.x == 0)
    out[0] = (red[0] + red[1] + red[2] + red[3]) * (1.0f / 4096.0f);
}

// ---------------- host ------------------------------------------------------
extern "C" void kernel_launch(void* const* d_in, const int* in_sizes, int n_in,
                              void* d_out, int out_size, void* d_ws, size_t ws_size,
                              hipStream_t stream) {
  (void)in_sizes; (void)n_in; (void)out_size; (void)ws_size;
  const float* X0 = (const float*)d_in[0];
  const float* X1 = (const float*)d_in[1];
  float* out = (float*)d_out;

  char* w = (char*)d_ws;
  auto carve = [&](size_t bytes) -> void* {
    void* r = (void*)w;
    w += (bytes + 255) & ~(size_t)255;
    return r;
  };
  u16*   Xh      = (u16*)carve(2ull * 8 * 512 * 16384 * 2);  // 256 MiB
  float* covP    = (float*)carve(4ull * 16 * MS * 4);        // 64 MiB
  float* covdiag = (float*)carve(16 * 512 * 4);
  u16* Ch  = (u16*)carve(8 * MS * 2); u16* Cl  = (u16*)carve(8 * MS * 2);
  u16* TCh = (u16*)carve(8 * MS * 2); u16* TCl = (u16*)carve(8 * MS * 2);
  float* G = (float*)carve(8ull * MS * 4);                   // 8 MiB
  u16* YS[2][4]; u16* ZS[2][4]; u16* TSb[2][4];
  for (int i = 0; i < 2; ++i)
    for (int a = 0; a < 4; ++a) {
      YS[i][a]  = (u16*)carve(8 * MS * 2);
      ZS[i][a]  = (u16*)carve(8 * MS * 2);
      TSb[i][a] = (u16*)carve(8 * MS * 2);
    }
  float* means = (float*)carve(8192 * 4);
  float* tr1P  = (float*)carve(64 * 4);
  float* tr2P  = (float*)carve(64 * 4);
  float* dotp  = (float*)carve(64 * 4);

  // 1) fp32 -> bf16 + means
  k_convert<<<2048, 256, 0, stream>>>(X0, X1, Xh, means);

  // 2) SYRK + fused finish/split
  k_syrk<<<640, 256, 0, stream>>>(Xh, covP);
  k_covfin2<<<2048, 256, 0, stream>>>(covP, means, covdiag, Ch, Cl, TCh, TCl);

  // 3) G = C @ TC (TC symmetric -> B-layout = TC itself)
  {
    GJ gj = {Ch, Cl, TCh, TCl, nullptr, nullptr, nullptr, nullptr, G, 1.0f, 0.0f};
    k_gg<<<512, 256, 0, stream>>>(gj, gj, 512);
  }
  k_trmom<<<64, 256, 0, stream>>>(G, tr1P, tr2P);

  // 4) X0 = G/nu: Y0, T0 = 1.5I - 0.5 X0, with transposes
  k_split_g<<<512, 256, 0, stream>>>(G, tr1P, tr2P,
                                     YS[0][0], YS[0][1], YS[0][2], YS[0][3],
                                     TSb[0][0], TSb[0][1], TSb[0][2], TSb[0][3]);

  // 5) NS trace-chain, 5 iterations total (trY5 via <Y4^T, T4>)
  {  // Y1 = Y0 @ T0
    GJ yj = {YS[0][0], YS[0][1], TSb[0][2], TSb[0][3],
             YS[1][0], YS[1][1], YS[1][2], YS[1][3], nullptr, 1.0f, 0.0f};
    k_gg<<<512, 256, 0, stream>>>(yj, yj, 512);
  }
  u16** Zk = TSb[0];  // Z1 = T0
  for (int k = 1; k <= 3; ++k) {
    u16** Yk = YS[k & 1];
    u16** Tk = TSb[k & 1];
    u16** Yn = YS[(k + 1) & 1];
    u16** Zn = ZS[(k + 1) & 1];
    GJ tj = {Zk[0], Zk[1], Yk[2], Yk[3],
             Tk[0], Tk[1], Tk[2], Tk[3], nullptr, -0.5f, 1.5f};
    k_gg<<<512, 256, 0, stream>>>(tj, tj, 512);
    GJ yj = {Yk[0], Yk[1], Tk[2], Tk[3],
             Yn[0], Yn[1], Yn[2], Yn[3], nullptr, 1.0f, 0.0f};
    GJ zj = {Tk[0], Tk[1], Zk[2], Zk[3],
             Zn[0], Zn[1], Zn[2], Zn[3], nullptr, 1.0f, 0.0f};
    if (k == 3) {               // only Y4^T and Z4 needed downstream
      yj.oH = nullptr; yj.oL = nullptr;
      zj.oTH = nullptr; zj.oTL = nullptr;
    }
    k_gg<<<1024, 256, 0, stream>>>(yj, zj, 512);
    Zk = Zn;
  }
  {  // T4 = 1.5I - 0.5 * Z4 @ Y4, normal layout only
    u16** Y4 = YS[0];
    GJ tj = {Zk[0], Zk[1], Y4[2], Y4[3],
             TSb[1][0], TSb[1][1], nullptr, nullptr, nullptr, -0.5f, 1.5f};
    k_gg<<<512, 256, 0, stream>>>(tj, tj, 512);
  }

  // 6) trace = <Y4^T, T4> = tr(Y5); loss
  k_dot<<<64, 256, 0, stream>>>(YS[0][2], YS[0][3], TSb[1][0], TSb[1][1], dotp);
  k_final<<<1, 256, 0, stream>>>(dotp, tr1P, tr2P, covdiag, means, out);
}